// Round 6
// baseline (415.149 us; speedup 1.0000x reference)
//
#include <hip/hip_runtime.h>

typedef __attribute__((ext_vector_type(8))) short short8;
typedef __attribute__((ext_vector_type(4))) float floatx4;

namespace {
constexpr int kB = 32, kCin = 256, kCout = 512, kL = 2048;
constexpr float kEps = 1e-5f;
constexpr float kInvN = 1.0f / (float)(kB * kL);   // 1/65536
constexpr int kKtot = kB * kL;                     // 65536
constexpr int BK = 32;
constexpr int KSTEPS = kCin / BK;                  // 8
constexpr int ST = 44;                             // padded LDS row stride (ushorts) for B tiles
constexpr int GRID_OUT = 4 * (kL / 128) * kB;      // 2048

// ---- tier A ws layout (float units). ~112.8 MiB ----
constexpr size_t A_ZC    = 0;           // ushort Zc[256][65536]
constexpr size_t A_ZT    = 8388608;     // ushort Zt[65536][256]
constexpr size_t A_XT    = 16777216;    // ushort Xt[65536][256]
constexpr size_t A_GPART = 25165824;    // float Gpart[256][16384]
constexpr size_t A_G     = 29360128;
constexpr size_t A_SZ    = 29425664;
constexpr size_t A_SC    = 29425920;
constexpr size_t A_SH    = 29426432;
constexpr size_t A_WBF   = 29426944;    // ushort Wbf[2][512][256]
constexpr size_t A_CNT   = 29558016;    // unsigned counter (grid barrier)
constexpr size_t A_END   = 29558080;
constexpr size_t A_BYTES = A_END * 4ull;           // 118,232,320 B

// ---- tier B ws layout (floats): R1 pipeline, 51.1 MiB ----
constexpr size_t B_ZC    = 0;
constexpr size_t B_GPART = 8388608;
constexpr size_t B_G     = 12582912;
constexpr size_t B_SZ    = 12648448;
constexpr size_t B_SC    = 12648704;
constexpr size_t B_SH    = 12649216;
constexpr size_t B_WBF   = 12649728;
constexpr size_t B_END   = 12780800;
constexpr size_t B_BYTES = B_END * 4ull;           // 51,123,200 B

// ---- fallback ws layout (floats) ----
constexpr size_t F_G = 0, F_SZ = 65536, F_SC = 65792, F_SH = 66304, F_WBF = 66816;
constexpr size_t F_END = 197888;
constexpr size_t F_BYTES = F_END * 4ull;
}

__device__ inline unsigned short f2bf(float f) {
    union { float f; unsigned u; } v; v.f = f;
    return (unsigned short)((v.u + 0x7fffu + ((v.u >> 16) & 1u)) >> 16);  // RNE
}
__device__ inline float bf2f(unsigned short h) {
    union { unsigned u; float f; } v; v.u = ((unsigned)h) << 16; return v.f;
}
__device__ inline unsigned pack2(float lo, float hi) {
    return (unsigned)f2bf(lo) | ((unsigned)f2bf(hi) << 16);
}
// single-instruction packed f32->bf16 (RNE)
__device__ inline unsigned cvtpk(float lo, float hi) {
    unsigned r;
    asm("v_cvt_pk_bf16_f32 %0, %1, %2" : "=v"(r) : "v"(lo), "v"(hi));
    return r;
}
// async 16B global->LDS (lane i lands at wave-uniform lds_base + i*16)
__device__ inline void cp16(const void* g, void* l) {
    __builtin_amdgcn_global_load_lds(
        (const __attribute__((address_space(1))) unsigned int*)g,
        (__attribute__((address_space(3))) unsigned int*)l, 16, 0, 0);
}
// device-scope grid barrier: grid must be <= 256 blocks (co-resident on 256 CUs by construction)
__device__ inline void gbar(unsigned* cnt, unsigned tgt) {
    __threadfence();                       // flush this block's writes (L2 wb, cross-XCD)
    __syncthreads();
    if (threadIdx.x == 0) {
        __hip_atomic_fetch_add(cnt, 1u, __ATOMIC_ACQ_REL, __HIP_MEMORY_SCOPE_AGENT);
        while (__hip_atomic_load(cnt, __ATOMIC_ACQUIRE, __HIP_MEMORY_SCOPE_AGENT) < tgt) {
            asm volatile("s_sleep 4");
        }
    }
    __syncthreads();
}

// ============================================================ tier B init: weights -> bf16, zero Sz + G
__global__ __launch_bounds__(256) void k_init(
    const float* __restrict__ pw_w, const float* __restrict__ res_w,
    unsigned short* __restrict__ Wbf, float* __restrict__ Sz, float* __restrict__ G)
{
    const int bid = blockIdx.x, tid = threadIdx.x;
    if (bid < 128) {
        const float* src = (bid < 64) ? pw_w : res_w;
        const int i = (bid & 63) * 2048 + tid * 8;
        float4 a = *(const float4*)(src + i);
        float4 b = *(const float4*)(src + i + 4);
        union { unsigned short u[8]; short8 v; } o;
        o.u[0]=f2bf(a.x); o.u[1]=f2bf(a.y); o.u[2]=f2bf(a.z); o.u[3]=f2bf(a.w);
        o.u[4]=f2bf(b.x); o.u[5]=f2bf(b.y); o.u[6]=f2bf(b.z); o.u[7]=f2bf(b.w);
        *(short8*)(Wbf + (bid < 64 ? 0 : 131072) + i) = o.v;
    } else if (bid == 128) {
        Sz[tid] = 0.f;
    } else {
        const int i = (bid - 129) * 2048 + tid * 8;
        float4 z4 = make_float4(0.f, 0.f, 0.f, 0.f);
        *(float4*)(G + i) = z4;
        *(float4*)(G + i + 4) = z4;
    }
}

// ============================================================ tier-B prep: x -> Zc bf16 [c][b*L], + Sz
__global__ __launch_bounds__(256, 4) void k_prepc(
    const float* __restrict__ x, const float* __restrict__ sw,
    unsigned short* __restrict__ Zc, float* __restrict__ Sz)
{
    __shared__ float wred[4];
    const int tid = threadIdx.x;
    const int lane = tid & 63, wave = tid >> 6;
    const int c = blockIdx.x >> 5;
    const int b = blockIdx.x & 31;
    const float w0 = sw[0], w1 = sw[1], w2 = sw[2];
    const int l = tid * 8;
    const float* xr = x + ((size_t)b * kCin + c) * kL + l;
    float4 c0 = *(const float4*)xr;
    float4 c1 = *(const float4*)(xr + 4);
    float4 pv = (l >= 4) ? *(const float4*)(xr - 4) : make_float4(0.f, 0.f, 0.f, 0.f);
    float V[12] = {pv.x,pv.y,pv.z,pv.w, c0.x,c0.y,c0.z,c0.w, c1.x,c1.y,c1.z,c1.w};
    union { unsigned short u[8]; short8 v; } o;
    float s = 0.f;
    #pragma unroll
    for (int j = 0; j < 8; ++j) {
        float z = fmaf(w0, V[j], fmaf(w1, V[j + 2], w2 * V[j + 4]));
        o.u[j] = f2bf(z);
        s += z;
    }
    *(short8*)(Zc + ((size_t)c << 16) + b * kL + l) = o.v;
    #pragma unroll
    for (int m = 1; m <= 32; m <<= 1) s += __shfl_xor(s, m, 64);
    if (lane == 0) wred[wave] = s;
    __syncthreads();
    if (tid == 0) atomicAdd(&Sz[c], (wred[0] + wred[1]) + (wred[2] + wred[3]));
}

// ============================================================ tier-A prep: x -> Zc + Zt + Xt (+ weights)
// 64-l tiles, 1024 data blocks (4/CU) + 128 weight blocks. Zeroes the grid-barrier counter.
__global__ __launch_bounds__(256, 4) void k_prep(
    const float* __restrict__ x, const float* __restrict__ sw,
    const float* __restrict__ pw_w, const float* __restrict__ res_w,
    unsigned short* __restrict__ Zc, unsigned short* __restrict__ Zt,
    unsigned short* __restrict__ Xt, unsigned short* __restrict__ Wbf,
    unsigned* __restrict__ cnt)
{
    __shared__ unsigned int T[64 * 129];
    const int bid = blockIdx.x, tid = threadIdx.x;
    if (bid >= 1024) {                       // ---- weight conversion blocks ----
        const int wb = bid - 1024;           // 0..127
        if (wb == 0 && tid == 0) *cnt = 0;   // reset grid-barrier counter for k_mid
        const float* src = (wb < 64) ? pw_w : res_w;
        const int i = (wb & 63) * 2048 + tid * 8;
        float4 a = *(const float4*)(src + i);
        float4 b = *(const float4*)(src + i + 4);
        union { unsigned short u[8]; short8 v; } o;
        o.u[0]=f2bf(a.x); o.u[1]=f2bf(a.y); o.u[2]=f2bf(a.z); o.u[3]=f2bf(a.w);
        o.u[4]=f2bf(b.x); o.u[5]=f2bf(b.y); o.u[6]=f2bf(b.z); o.u[7]=f2bf(b.w);
        *(short8*)(Wbf + (wb < 64 ? 0 : 131072) + i) = o.v;
        return;
    }
    const int lgrp = tid & 15;          // l-group: 4 l each -> 64 l
    const int cp   = tid >> 4;          // c-pair lane 0..15
    const int b  = bid >> 5;
    const int lt = bid & 31;
    const int lh = lt * 64;
    const float w0 = sw[0], w1 = sw[1], w2 = sw[2];
    const float* xb = x + (size_t)b * kCin * kL;

    const int lg4 = lh + lgrp * 4;
    const bool hp = lg4 >= 4;
    // ---- pass Z ----
    #pragma unroll
    for (int ci = 0; ci < 8; ++ci) {
        const int c = (ci * 16 + cp) * 2;
        const float* r0 = xb + (size_t)c * kL + lg4;
        const float* r1 = r0 + kL;
        float4 c0 = *(const float4*)r0;
        float4 p0 = hp ? *(const float4*)(r0 - 4) : make_float4(0.f,0.f,0.f,0.f);
        float4 c1 = *(const float4*)r1;
        float4 p1 = hp ? *(const float4*)(r1 - 4) : make_float4(0.f,0.f,0.f,0.f);
        float za[4], zb[4];
        za[0] = fmaf(w0, p0.x, fmaf(w1, p0.z, w2 * c0.x));
        za[1] = fmaf(w0, p0.y, fmaf(w1, p0.w, w2 * c0.y));
        za[2] = fmaf(w0, p0.z, fmaf(w1, c0.x, w2 * c0.z));
        za[3] = fmaf(w0, p0.w, fmaf(w1, c0.y, w2 * c0.w));
        zb[0] = fmaf(w0, p1.x, fmaf(w1, p1.z, w2 * c1.x));
        zb[1] = fmaf(w0, p1.y, fmaf(w1, p1.w, w2 * c1.y));
        zb[2] = fmaf(w0, p1.z, fmaf(w1, c1.x, w2 * c1.z));
        zb[3] = fmaf(w0, p1.w, fmaf(w1, c1.y, w2 * c1.w));
        uint2 wa = make_uint2(cvtpk(za[0], za[1]), cvtpk(za[2], za[3]));
        uint2 wb2 = make_uint2(cvtpk(zb[0], zb[1]), cvtpk(zb[2], zb[3]));
        *(uint2*)(Zc + ((size_t)c       << 16) + (size_t)b * kL + lg4) = wa;
        *(uint2*)(Zc + ((size_t)(c + 1) << 16) + (size_t)b * kL + lg4) = wb2;
        #pragma unroll
        for (int j = 0; j < 4; ++j)
            T[(lgrp * 4 + j) * 129 + ci * 16 + cp] = cvtpk(za[j], zb[j]);
    }
    __syncthreads();
    {
        const int l = tid >> 2;
        #pragma unroll
        for (int gi = 0; gi < 8; ++gi) {
            const int g = (tid & 3) + gi * 4;
            uint4 v = *(const uint4*)&T[l * 129 + g * 4];
            *(uint4*)(Zt + (size_t)(b * kL + lh + l) * 256 + g * 8) = v;
        }
    }
    __syncthreads();
    // ---- pass X (re-reads L2-hot) ----
    #pragma unroll
    for (int ci = 0; ci < 8; ++ci) {
        const int c = (ci * 16 + cp) * 2;
        const float* r0 = xb + (size_t)c * kL + lg4;
        float4 c0 = *(const float4*)r0;
        float4 c1 = *(const float4*)(r0 + kL);
        #pragma unroll
        for (int j = 0; j < 4; ++j) {
            const float a = (&c0.x)[j];
            const float bb = (&c1.x)[j];
            T[(lgrp * 4 + j) * 129 + ci * 16 + cp] = cvtpk(a, bb);
        }
    }
    __syncthreads();
    {
        const int l = tid >> 2;
        #pragma unroll
        for (int gi = 0; gi < 8; ++gi) {
            const int g = (tid & 3) + gi * 4;
            uint4 v = *(const uint4*)&T[l * 129 + g * 4];
            *(uint4*)(Xt + (size_t)(b * kL + lh + l) * 256 + g * 8) = v;
        }
    }
}

// ============================================================ tier-A fused middle: gram + gred + Sz + bnp
// grid = 256 blocks (== #CUs, co-resident by construction); device spin barrier between phases.
__global__ __launch_bounds__(256, 2) void k_mid(
    const unsigned short* __restrict__ Zc, float* __restrict__ Gpart,
    float* __restrict__ G, float* __restrict__ Sz,
    const unsigned short* __restrict__ Wbf, const float* __restrict__ gamma,
    const float* __restrict__ beta, float* __restrict__ sc_out, float* __restrict__ sh_out,
    unsigned* __restrict__ cnt)
{
    __shared__ __align__(16) unsigned short Zm[4][128 * 32];
    __shared__ __align__(16) unsigned short Zn[4][128 * 32];
    __shared__ float tbuf[256];
    __shared__ float red[8];

    const int tid = threadIdx.x, bid = blockIdx.x;
    const int lane = tid & 63, wave = tid >> 6;
    const int fr = lane & 15, fq = lane >> 4;

    // ================= phase 1: gram partials =================
    {
        const int q = bid & 3;
        const int h = bid >> 2;
        const int qm = (q >> 1) * 128, qn = (q & 1) * 128;
        const int wm = (wave >> 1) * 64, wn = (wave & 1) * 64;

        const int srow = wave * 32 + (lane >> 2);
        const int gsw = (((lane & 3) ^ ((lane >> 3) & 3)) * 8);
        const size_t kbase = (size_t)h * 1024 + gsw;
        const unsigned short* gm0 = Zc + (size_t)(qm + srow) * kKtot + kbase;
        const unsigned short* gm1 = gm0 + (size_t)16 * kKtot;
        const unsigned short* gn0 = Zc + (size_t)(qn + srow) * kKtot + kbase;
        const unsigned short* gn1 = gn0 + (size_t)16 * kKtot;

        const int rsw = (fr >> 1) & 3;
        int aoff[4], boff[4];
        #pragma unroll
        for (int mi = 0; mi < 4; ++mi) aoff[mi] = (wm + mi * 16 + fr) * 32 + ((fq ^ rsw) * 8);
        #pragma unroll
        for (int ni = 0; ni < 4; ++ni) boff[ni] = (wn + ni * 16 + fr) * 32 + ((fq ^ rsw) * 8);

        floatx4 acc[4][4];
        #pragma unroll
        for (int mi = 0; mi < 4; ++mi)
            #pragma unroll
            for (int ni = 0; ni < 4; ++ni) acc[mi][ni] = (floatx4){0.f, 0.f, 0.f, 0.f};

        auto STAGE = [&](const int sbuf) {
            cp16(gm0, &Zm[sbuf][wave * 1024]); cp16(gm1, &Zm[sbuf][wave * 1024 + 512]);
            cp16(gn0, &Zn[sbuf][wave * 1024]); cp16(gn1, &Zn[sbuf][wave * 1024 + 512]);
            gm0 += 32; gm1 += 32; gn0 += 32; gn1 += 32;
        };

        STAGE(0); STAGE(1); STAGE(2);
        for (int t = 0; t < 32; ++t) {
            if (t < 30)       asm volatile("s_waitcnt vmcnt(8)" ::: "memory");
            else if (t == 30) asm volatile("s_waitcnt vmcnt(4)" ::: "memory");
            else              asm volatile("s_waitcnt vmcnt(0)" ::: "memory");
            asm volatile("s_barrier" ::: "memory");
            if (t < 29) STAGE((t + 3) & 3);
            const unsigned short* rm = &Zm[t & 3][0];
            const unsigned short* rn = &Zn[t & 3][0];
            short8 bfp[4];
            #pragma unroll
            for (int ni = 0; ni < 4; ++ni)
                bfp[ni] = *(const short8*)&rn[boff[ni]];
            #pragma unroll
            for (int mi = 0; mi < 4; ++mi) {
                short8 af = *(const short8*)&rm[aoff[mi]];
                #pragma unroll
                for (int ni = 0; ni < 4; ++ni)
                    acc[mi][ni] = __builtin_amdgcn_mfma_f32_16x16x32_bf16(af, bfp[ni], acc[mi][ni], 0, 0, 0);
            }
        }

        float* gp = Gpart + (size_t)bid * 16384;
        #pragma unroll
        for (int mi = 0; mi < 4; ++mi)
            #pragma unroll
            for (int ni = 0; ni < 4; ++ni) {
                const int col = wn + ni * 16 + fr;
                #pragma unroll
                for (int r = 0; r < 4; ++r)
                    gp[(wm + mi * 16 + fq * 4 + r) * 128 + col] = acc[mi][ni][r];
            }
    }

    gbar(cnt, 256);

    // ================= phase 2: reduce Gpart -> G, Sz row =================
    {
        const int q = bid >> 6;
        const int e = (bid & 63) * 256 + tid;
        const int qm = (q >> 1) * 128, qn = (q & 1) * 128;
        const float* p = Gpart + (size_t)q * 16384 + e;
        float s0 = 0.f, s1 = 0.f, s2 = 0.f, s3 = 0.f;
        #pragma unroll 4
        for (int hh = 0; hh < 64; hh += 4) {
            s0 += p[(size_t)(hh + 0) * 65536];
            s1 += p[(size_t)(hh + 1) * 65536];
            s2 += p[(size_t)(hh + 2) * 65536];
            s3 += p[(size_t)(hh + 3) * 65536];
        }
        G[(qm + (e >> 7)) * 256 + qn + (e & 127)] = (s0 + s1) + (s2 + s3);

        // Sz for c = bid
        const unsigned short* row = Zc + ((size_t)bid << 16);
        float s = 0.f;
        #pragma unroll 4
        for (int i = 0; i < 32; ++i) {
            short8 v = *(const short8*)(row + (size_t)i * 2048 + tid * 8);
            #pragma unroll
            for (int j = 0; j < 8; ++j) s += bf2f((unsigned short)v[j]);
        }
        #pragma unroll
        for (int m = 1; m <= 32; m <<= 1) s += __shfl_xor(s, m, 64);
        if (lane == 0) red[wave] = s;
        __syncthreads();
        if (tid == 0) Sz[bid] = (red[0] + red[1]) + (red[2] + red[3]);
    }

    gbar(cnt, 512);

    // ================= phase 3: BN params (o = bid, bid+256) =================
    #pragma unroll
    for (int oo = 0; oo < 2; ++oo) {
        const int o = bid + oo * 256;
        tbuf[tid] = bf2f(Wbf[(size_t)o * kCin + tid]);
        __syncthreads();
        const float myt = tbuf[tid];
        float q0 = 0.f, q1 = 0.f, q2 = 0.f, q3 = 0.f;
        #pragma unroll 4
        for (int j = 0; j < 256; j += 4) {
            q0 = fmaf(tbuf[j + 0], G[(j + 0) * 256 + tid], q0);
            q1 = fmaf(tbuf[j + 1], G[(j + 1) * 256 + tid], q1);
            q2 = fmaf(tbuf[j + 2], G[(j + 2) * 256 + tid], q2);
            q3 = fmaf(tbuf[j + 3], G[(j + 3) * 256 + tid], q3);
        }
        float qv = ((q0 + q1) + (q2 + q3)) * myt;
        float mv = myt * Sz[tid];
        #pragma unroll
        for (int off = 1; off <= 32; off <<= 1) {
            qv += __shfl_xor(qv, off, 64);
            mv += __shfl_xor(mv, off, 64);
        }
        if (lane == 0) { red[wave] = qv; red[4 + wave] = mv; }
        __syncthreads();
        if (tid == 0) {
            const float qt = (red[0] + red[1]) + (red[2] + red[3]);
            const float mt = (red[4] + red[5]) + (red[6] + red[7]);
            const float mean = mt * kInvN;
            const float var = qt * kInvN - mean * mean;
            const float s = gamma[o] * rsqrtf(var + kEps);
            sc_out[o] = s;
            sh_out[o] = fmaf(-mean, s, beta[o]);
        }
        __syncthreads();
    }
}

// ============================================================ tier-B Gram GEMM (4-buffer pipeline)
__global__ __launch_bounds__(256, 2) void k_gram2(
    const unsigned short* __restrict__ Zc, float* __restrict__ Gpart)
{
    __shared__ __align__(16) unsigned short Zm[4][128 * 32];
    __shared__ __align__(16) unsigned short Zn[4][128 * 32];

    const int tid = threadIdx.x;
    const int lane = tid & 63, wave = tid >> 6;
    const int fr = lane & 15, fq = lane >> 4;
    const int q = blockIdx.x & 3;
    const int h = blockIdx.x >> 2;
    const int qm = (q >> 1) * 128, qn = (q & 1) * 128;
    const int wm = (wave >> 1) * 64, wn = (wave & 1) * 64;

    const int srow = wave * 32 + (lane >> 2);
    const int gsw = (((lane & 3) ^ ((lane >> 3) & 3)) * 8);
    const size_t kbase = (size_t)h * 1024 + gsw;
    const unsigned short* gm0 = Zc + (size_t)(qm + srow) * kKtot + kbase;
    const unsigned short* gm1 = gm0 + (size_t)16 * kKtot;
    const unsigned short* gn0 = Zc + (size_t)(qn + srow) * kKtot + kbase;
    const unsigned short* gn1 = gn0 + (size_t)16 * kKtot;

    const int rsw = (fr >> 1) & 3;
    int aoff[4], boff[4];
    #pragma unroll
    for (int mi = 0; mi < 4; ++mi) aoff[mi] = (wm + mi * 16 + fr) * 32 + ((fq ^ rsw) * 8);
    #pragma unroll
    for (int ni = 0; ni < 4; ++ni) boff[ni] = (wn + ni * 16 + fr) * 32 + ((fq ^ rsw) * 8);

    floatx4 acc[4][4];
    #pragma unroll
    for (int mi = 0; mi < 4; ++mi)
        #pragma unroll
        for (int ni = 0; ni < 4; ++ni) acc[mi][ni] = (floatx4){0.f, 0.f, 0.f, 0.f};

    auto STAGE = [&](const int sbuf) {
        cp16(gm0, &Zm[sbuf][wave * 1024]); cp16(gm1, &Zm[sbuf][wave * 1024 + 512]);
        cp16(gn0, &Zn[sbuf][wave * 1024]); cp16(gn1, &Zn[sbuf][wave * 1024 + 512]);
        gm0 += 32; gm1 += 32; gn0 += 32; gn1 += 32;
    };

    STAGE(0); STAGE(1); STAGE(2);
    for (int t = 0; t < 32; ++t) {
        if (t < 30)       asm volatile("s_waitcnt vmcnt(8)" ::: "memory");
        else if (t == 30) asm volatile("s_waitcnt vmcnt(4)" ::: "memory");
        else              asm volatile("s_waitcnt vmcnt(0)" ::: "memory");
        asm volatile("s_barrier" ::: "memory");
        if (t < 29) STAGE((t + 3) & 3);
        const unsigned short* rm = &Zm[t & 3][0];
        const unsigned short* rn = &Zn[t & 3][0];
        short8 bfp[4];
        #pragma unroll
        for (int ni = 0; ni < 4; ++ni)
            bfp[ni] = *(const short8*)&rn[boff[ni]];
        #pragma unroll
        for (int mi = 0; mi < 4; ++mi) {
            short8 af = *(const short8*)&rm[aoff[mi]];
            #pragma unroll
            for (int ni = 0; ni < 4; ++ni)
                acc[mi][ni] = __builtin_amdgcn_mfma_f32_16x16x32_bf16(af, bfp[ni], acc[mi][ni], 0, 0, 0);
        }
    }

    float* gp = Gpart + (size_t)blockIdx.x * 16384;
    #pragma unroll
    for (int mi = 0; mi < 4; ++mi)
        #pragma unroll
        for (int ni = 0; ni < 4; ++ni) {
            const int col = wn + ni * 16 + fr;
            #pragma unroll
            for (int r = 0; r < 4; ++r)
                gp[(wm + mi * 16 + fq * 4 + r) * 128 + col] = acc[mi][ni][r];
        }
}

// ============================================================ tier-B reduce + Sz
__global__ __launch_bounds__(256) void k_gred(
    const float* __restrict__ Gpart, const unsigned short* __restrict__ Zc,
    float* __restrict__ G, float* __restrict__ Sz)
{
    const int bid = blockIdx.x, tid = threadIdx.x;
    if (bid < 256) {
        const int q = bid >> 6;
        const int e = (bid & 63) * 256 + tid;
        const int qm = (q >> 1) * 128, qn = (q & 1) * 128;
        const float* p = Gpart + (size_t)q * 16384 + e;
        float s0 = 0.f, s1 = 0.f, s2 = 0.f, s3 = 0.f;
        #pragma unroll 4
        for (int hh = 0; hh < 64; hh += 4) {
            s0 += p[(size_t)(hh + 0) * 65536];
            s1 += p[(size_t)(hh + 1) * 65536];
            s2 += p[(size_t)(hh + 2) * 65536];
            s3 += p[(size_t)(hh + 3) * 65536];
        }
        G[(qm + (e >> 7)) * 256 + qn + (e & 127)] = (s0 + s1) + (s2 + s3);
    } else {
        __shared__ float wred[4];
        const int lane = tid & 63, wave = tid >> 6;
        const int r0 = (bid - 256) * 8;
        for (int r = 0; r < 8; ++r) {
            const unsigned short* row = Zc + ((size_t)(r0 + r) << 16);
            float s = 0.f;
            #pragma unroll 4
            for (int i = 0; i < 32; ++i) {
                short8 v = *(const short8*)(row + (size_t)i * 2048 + tid * 8);
                #pragma unroll
                for (int j = 0; j < 8; ++j) s += bf2f((unsigned short)v[j]);
            }
            #pragma unroll
            for (int m = 1; m <= 32; m <<= 1) s += __shfl_xor(s, m, 64);
            if (lane == 0) wred[wave] = s;
            __syncthreads();
            if (tid == 0) Sz[r0 + r] = (wred[0] + wred[1]) + (wred[2] + wred[3]);
            __syncthreads();
        }
    }
}

// ============================================================ tier-B BN params
__global__ __launch_bounds__(256) void k_bnp(
    const float* __restrict__ G, const float* __restrict__ Sz,
    const unsigned short* __restrict__ Wbf, const float* __restrict__ gamma,
    const float* __restrict__ beta, float* __restrict__ sc_out, float* __restrict__ sh_out)
{
    __shared__ float t[256];
    __shared__ float redq[4], redm[4];
    const int o = blockIdx.x, c = threadIdx.x;
    const int lane = c & 63, wave = c >> 6;
    t[c] = bf2f(Wbf[(size_t)o * kCin + c]);
    __syncthreads();
    const float myt = t[c];
    float q0 = 0.f, q1 = 0.f, q2 = 0.f, q3 = 0.f;
    #pragma unroll 4
    for (int j = 0; j < 256; j += 4) {
        q0 = fmaf(t[j + 0], G[(j + 0) * 256 + c], q0);
        q1 = fmaf(t[j + 1], G[(j + 1) * 256 + c], q1);
        q2 = fmaf(t[j + 2], G[(j + 2) * 256 + c], q2);
        q3 = fmaf(t[j + 3], G[(j + 3) * 256 + c], q3);
    }
    float q = ((q0 + q1) + (q2 + q3)) * myt;
    float m = myt * Sz[c];
    #pragma unroll
    for (int off = 1; off <= 32; off <<= 1) {
        q += __shfl_xor(q, off, 64);
        m += __shfl_xor(m, off, 64);
    }
    if (lane == 0) { redq[wave] = q; redm[wave] = m; }
    __syncthreads();
    if (c == 0) {
        const float qt = (redq[0] + redq[1]) + (redq[2] + redq[3]);
        const float mt = (redm[0] + redm[1]) + (redm[2] + redm[3]);
        const float mean = mt * kInvN;
        const float var = qt * kInvN - mean * mean;
        const float s = gamma[o] * rsqrtf(var + kEps);
        sc_out[o] = s;
        sh_out[o] = fmaf(-mean, s, beta[o]);
    }
}

// ============================================================ fallback gram (VALU version)
__global__ __launch_bounds__(256, 2) void k_gram_fb(
    const float* __restrict__ x, const float* __restrict__ sw,
    float* __restrict__ G, float* __restrict__ Sz)
{
    __shared__ __align__(16) unsigned short Zt[256 * ST];
    const int tid = threadIdx.x;
    const int lane = tid & 63, wave = tid >> 6;
    const int fr = lane & 15, fq = lane >> 4;
    const int quad = blockIdx.x & 3;
    const int chunk = blockIdx.x >> 2;
    const int qm = (quad >> 1) * 128, qn = (quad & 1) * 128;
    const int b = chunk >> 2;
    const int l0 = (chunk & 3) * 512;
    const bool dosz = (quad == 0);
    const float w0 = sw[0], w1 = sw[1], w2 = sw[2];
    const float* xb = x + (size_t)b * kCin * kL;

    floatx4 acc[4][4];
    #pragma unroll
    for (int mi = 0; mi < 4; ++mi)
        #pragma unroll
        for (int ni = 0; ni < 4; ++ni) acc[mi][ni] = (floatx4){0.f, 0.f, 0.f, 0.f};

    const int cr = tid >> 3;
    const int loff = (tid & 7) * 4;
    float sz[8] = {0.f,0.f,0.f,0.f,0.f,0.f,0.f,0.f};
    int aOff[4], bOff[4];
    #pragma unroll
    for (int mi = 0; mi < 4; ++mi) aOff[mi] = (qm + (wave >> 1) * 64 + mi * 16 + fr) * ST + fq * 8;
    #pragma unroll
    for (int ni = 0; ni < 4; ++ni) bOff[ni] = (qn + (wave & 1) * 64 + ni * 16 + fr) * ST + fq * 8;

    for (int ks = 0; ks < 16; ++ks) {
        const int lk = l0 + ks * BK;
        const bool hasprv = (lk + loff) >= 4;
        __syncthreads();
        #pragma unroll
        for (int p = 0; p < 8; ++p) {
            const int c = p * 32 + cr;
            const float* bp = xb + (size_t)c * kL + lk + loff;
            float4 cur = *(const float4*)bp;
            float4 prv = hasprv ? *(const float4*)(bp - 4) : make_float4(0.f,0.f,0.f,0.f);
            float z0 = fmaf(w0, prv.x, fmaf(w1, prv.z, w2 * cur.x));
            float z1 = fmaf(w0, prv.y, fmaf(w1, prv.w, w2 * cur.y));
            float z2 = fmaf(w0, prv.z, fmaf(w1, cur.x, w2 * cur.z));
            float z3 = fmaf(w0, prv.w, fmaf(w1, cur.y, w2 * cur.w));
            *(unsigned*)&Zt[c * ST + loff]     = pack2(z0, z1);
            *(unsigned*)&Zt[c * ST + loff + 2] = pack2(z2, z3);
            if (dosz) sz[p] += (z0 + z1) + (z2 + z3);
        }
        __syncthreads();
        short8 bf_[4];
        #pragma unroll
        for (int ni = 0; ni < 4; ++ni) bf_[ni] = *(const short8*)&Zt[bOff[ni]];
        #pragma unroll
        for (int mi = 0; mi < 4; ++mi) {
            short8 af = *(const short8*)&Zt[aOff[mi]];
            #pragma unroll
            for (int ni = 0; ni < 4; ++ni)
                acc[mi][ni] = __builtin_amdgcn_mfma_f32_16x16x32_bf16(af, bf_[ni], acc[mi][ni], 0, 0, 0);
        }
    }
    #pragma unroll
    for (int mi = 0; mi < 4; ++mi) {
        const int growb = qm + (wave >> 1) * 64 + mi * 16 + fq * 4;
        #pragma unroll
        for (int ni = 0; ni < 4; ++ni) {
            const int gcol = qn + (wave & 1) * 64 + ni * 16 + fr;
            #pragma unroll
            for (int r = 0; r < 4; ++r)
                atomicAdd(&G[(growb + r) * 256 + gcol], acc[mi][ni][r]);
        }
    }
    if (dosz) {
        #pragma unroll
        for (int p = 0; p < 8; ++p) {
            float s = sz[p];
            s += __shfl_xor(s, 1, 64);
            s += __shfl_xor(s, 2, 64);
            s += __shfl_xor(s, 4, 64);
            if ((lane & 7) == 0) atomicAdd(&Sz[p * 32 + cr], s);
        }
    }
}

// ============================================================ tier B/C output (R1 version)
__global__ __launch_bounds__(256, 2) void k_out2(
    const float* __restrict__ x, const float* __restrict__ sw,
    const unsigned short* __restrict__ Wbf,
    const float* __restrict__ res_b, const float* __restrict__ sc_arr,
    const float* __restrict__ sh_arr, float* __restrict__ out)
{
    __shared__ __align__(16) unsigned short As[2 * 128 * 32];
    __shared__ __align__(16) unsigned short Bz[128 * ST];
    __shared__ __align__(16) unsigned short Bx[128 * ST];

    const int tid = threadIdx.x;
    const int lane = tid & 63, wave = tid >> 6;
    const int fr = lane & 15, fq = lane >> 4;
    const int wo = (wave >> 1) * 64;
    const int wl = (wave & 1) * 64;

    const int pid = blockIdx.x;
    const int slot = pid >> 3;
    const int mt = slot & 3;
    const int u = (pid & 7) * 64 + (slot >> 2);
    const int lt = u & 15;
    const int b = u >> 4;
    const int o0 = mt * 128, l0 = lt * 128;

    const float w0 = sw[0], w1 = sw[1], w2 = sw[2];
    const float* xb = x + (size_t)b * kCin * kL;

    floatx4 accY[4][4], accR[4][4];
    #pragma unroll
    for (int mi = 0; mi < 4; ++mi)
        #pragma unroll
        for (int ni = 0; ni < 4; ++ni) {
            accY[mi][ni] = (floatx4){0.f, 0.f, 0.f, 0.f};
            accR[mi][ni] = (floatx4){0.f, 0.f, 0.f, 0.f};
        }

    const int gsw = (((lane & 3) ^ ((lane >> 3) & 3)) * 8);
    const unsigned short* wsrc[4];
    unsigned short* wdst[4];
    #pragma unroll
    for (int j = 0; j < 4; ++j) {
        const int m = j >> 1;
        const int r = (j & 1) * 64 + wave * 16 + (lane >> 2);
        wsrc[j] = Wbf + (size_t)m * 131072 + (size_t)(o0 + r) * kCin + gsw;
        wdst[j] = As + j * 2048 + wave * 512;
    }

    const int rsw = (fr >> 1) & 3;
    int aOffP[4], bOff[4];
    #pragma unroll
    for (int mi = 0; mi < 4; ++mi)
        aOffP[mi] = (wo + mi * 16 + fr) * 32 + ((fq ^ rsw) * 8);
    #pragma unroll
    for (int ni = 0; ni < 4; ++ni) bOff[ni] = (wl + ni * 16 + fr) * ST + fq * 8;

    const int c2 = (tid & 15) * 2;
    const int ll = (tid >> 4) * 8;
    const bool hasprv = (l0 + ll) >= 4;
    float4 xpa, xa0, xa1, xpb, xb0, xb1;
    auto LOAD = [&](int ks) {
        const int k0 = ks * BK;
        const float* base0 = xb + (size_t)(k0 + c2) * kL + l0 + ll;
        const float* base1 = base0 + kL;
        xpa = hasprv ? *(const float4*)(base0 - 4) : make_float4(0.f,0.f,0.f,0.f);
        xa0 = *(const float4*)(base0);
        xa1 = *(const float4*)(base0 + 4);
        xpb = hasprv ? *(const float4*)(base1 - 4) : make_float4(0.f,0.f,0.f,0.f);
        xb0 = *(const float4*)(base1);
        xb1 = *(const float4*)(base1 + 4);
    };
    auto PACKB = [&]() {
        float A[12]  = {xpa.x,xpa.y,xpa.z,xpa.w, xa0.x,xa0.y,xa0.z,xa0.w, xa1.x,xa1.y,xa1.z,xa1.w};
        float Bv[12] = {xpb.x,xpb.y,xpb.z,xpb.w, xb0.x,xb0.y,xb0.z,xb0.w, xb1.x,xb1.y,xb1.z,xb1.w};
        #pragma unroll
        for (int j = 0; j < 8; ++j) {
            float zA = fmaf(w0, A[j],  fmaf(w1, A[j + 2],  w2 * A[j + 4]));
            float zB = fmaf(w0, Bv[j], fmaf(w1, Bv[j + 2], w2 * Bv[j + 4]));
            *(unsigned*)&Bz[(ll + j) * ST + c2] = cvtpk(zA, zB);
            *(unsigned*)&Bx[(ll + j) * ST + c2] = cvtpk(A[j + 4], Bv[j + 4]);
        }
    };

    LOAD(0);
    for (int ks = 0; ks < KSTEPS; ++ks) {
        #pragma unroll
        for (int j = 0; j < 4; ++j) { cp16(wsrc[j], wdst[j]); wsrc[j] += BK; }
        PACKB();
        __syncthreads();
        if (ks < KSTEPS - 1) LOAD(ks + 1);
        short8 vz[4], vx[4];
        #pragma unroll
        for (int ni = 0; ni < 4; ++ni) {
            vz[ni] = *(const short8*)&Bz[bOff[ni]];
            vx[ni] = *(const short8*)&Bx[bOff[ni]];
        }
        #pragma unroll
        for (int mi = 0; mi < 4; ++mi) {
            short8 ap = *(const short8*)&As[aOffP[mi]];
            short8 ar = *(const short8*)&As[4096 + aOffP[mi]];
            #pragma unroll
            for (int ni = 0; ni < 4; ++ni) {
                accY[mi][ni] = __builtin_amdgcn_mfma_f32_16x16x32_bf16(ap, vz[ni], accY[mi][ni], 0, 0, 0);
                accR[mi][ni] = __builtin_amdgcn_mfma_f32_16x16x32_bf16(ar, vx[ni], accR[mi][ni], 0, 0, 0);
            }
        }
        __syncthreads();
    }

    #pragma unroll
    for (int mi = 0; mi < 4; ++mi)
        #pragma unroll
        for (int r = 0; r < 4; ++r) {
            const int o = o0 + wo + mi * 16 + fq * 4 + r;
            const float sc = sc_arr[o], sh = sh_arr[o], rb = res_b[o];
            const size_t orow = ((size_t)b * kCout + o) * kL + l0 + wl + fr;
            #pragma unroll
            for (int ni = 0; ni < 4; ++ni) {
                float yn = fmaxf(fmaf(accY[mi][ni][r], sc, sh), 0.f);
                float rr = accR[mi][ni][r] + rb;
                out[orow + ni * 16] = fmaxf(yn + rr, 0.f);
            }
        }
}

// ============================================================ tier-A output: pure cp16 dual GEMM,
// double-buffered LDS, counted vmcnt (8 cp16/wave per stage stay in flight across barriers)
__global__ __launch_bounds__(256, 2) void k_out3(
    const unsigned short* __restrict__ Zt, const unsigned short* __restrict__ Xt,
    const unsigned short* __restrict__ Wbf,
    const float* __restrict__ res_b, const float* __restrict__ sc_arr,
    const float* __restrict__ sh_arr, float* __restrict__ out)
{
    __shared__ __align__(16) unsigned short Lz[2][128 * 32];
    __shared__ __align__(16) unsigned short Lx[2][128 * 32];
    __shared__ __align__(16) unsigned short Wp[2][128 * 32];
    __shared__ __align__(16) unsigned short Wr[2][128 * 32];

    const int tid = threadIdx.x;
    const int lane = tid & 63, wave = tid >> 6;
    const int fr = lane & 15, fq = lane >> 4;
    const int wl  = (wave >> 1) * 64;
    const int wo2 = (wave & 1) * 64;

    const int pid = blockIdx.x;
    const int slot = pid >> 3;
    const int mt = slot & 3;
    const int u = (pid & 7) * 64 + (slot >> 2);
    const int lt = u & 15;
    const int b = u >> 4;
    const int o0 = mt * 128, l0 = lt * 128;

    floatx4 accY[4][4], accR[4][4];
    #pragma unroll
    for (int mi = 0; mi < 4; ++mi)
        #pragma unroll
        for (int ni = 0; ni < 4; ++ni) {
            accY[mi][ni] = (floatx4){0.f, 0.f, 0.f, 0.f};
            accR[mi][ni] = (floatx4){0.f, 0.f, 0.f, 0.f};
        }

    const int srow = lane >> 2;
    const int gsw = (((lane & 3) ^ ((lane >> 3) & 3)) * 8);
    const unsigned short* gz0 = Zt + (size_t)(b * kL + l0 + wave * 32 + srow) * 256 + gsw;
    const unsigned short* gz1 = gz0 + 16 * 256;
    const unsigned short* gx0 = Xt + (size_t)(b * kL + l0 + wave * 32 + srow) * 256 + gsw;
    const unsigned short* gx1 = gx0 + 16 * 256;
    const unsigned short* gp0 = Wbf + (size_t)(o0 + wave * 32 + srow) * 256 + gsw;
    const unsigned short* gp1 = gp0 + 16 * 256;
    const unsigned short* gr0 = gp0 + 131072;
    const unsigned short* gr1 = gr0 + 16 * 256;

    auto STAGE = [&](const int buf) {
        cp16(gz0, &Lz[buf][wave * 1024]); cp16(gz1, &Lz[buf][wave * 1024 + 512]);
        cp16(gx0, &Lx[buf][wave * 1024]); cp16(gx1, &Lx[buf][wave * 1024 + 512]);
        cp16(gp0, &Wp[buf][wave * 1024]); cp16(gp1, &Wp[buf][wave * 1024 + 512]);
        cp16(gr0, &Wr[buf][wave * 1024]); cp16(gr1, &Wr[buf][wave * 1024 + 512]);
        gz0 += 32; gz1 += 32; gx0 += 32; gx1 += 32;
        gp0 += 32; gp1 += 32; gr0 += 32; gr1 += 32;
    };

    const int rsw = (fr >> 1) & 3;
    int aoff[4], boff[4];
    #pragma unroll
    for (int mi = 0; mi < 4; ++mi) aoff[mi] = (wl + mi * 16 + fr) * 32 + ((fq ^ rsw) * 8);
    #pragma unroll
    for (int ni = 0; ni < 4; ++ni) boff[ni] = (wo2 + ni * 16 + fr) * 32 + ((fq ^ rsw) * 8);

    STAGE(0); STAGE(1);
    #pragma unroll
    for (int ks = 0; ks < KSTEPS; ++ks) {
        if (ks < KSTEPS - 1) asm volatile("s_waitcnt vmcnt(8)" ::: "memory");
        else                 asm volatile("s_waitcnt vmcnt(0)" ::: "memory");
        asm volatile("s_barrier" ::: "memory");
        const int rb_ = ks & 1;
        short8 bp[4], br[4];
        #pragma unroll
        for (int ni = 0; ni < 4; ++ni) {
            bp[ni] = *(const short8*)&Wp[rb_][boff[ni]];
            br[ni] = *(const short8*)&Wr[rb_][boff[ni]];
        }
        #pragma unroll
        for (int mi = 0; mi < 4; ++mi) {
            short8 az = *(const short8*)&Lz[rb_][aoff[mi]];
            short8 ax = *(const short8*)&Lx[rb_][aoff[mi]];
            #pragma unroll
            for (int ni = 0; ni < 4; ++ni) {
                accY[mi][ni] = __builtin_amdgcn_mfma_f32_16x16x32_bf16(az, bp[ni], accY[mi][ni], 0, 0, 0);
                accR[mi][ni] = __builtin_amdgcn_mfma_f32_16x16x32_bf16(ax, br[ni], accR[mi][ni], 0, 0, 0);
            }
        }
        asm volatile("s_barrier" ::: "memory");
        if (ks < KSTEPS - 2) STAGE(ks & 1);
    }

    #pragma unroll
    for (int ni = 0; ni < 4; ++ni) {
        const int o = o0 + wo2 + ni * 16 + fr;
        const float sc = sc_arr[o], sh = sh_arr[o], rb = res_b[o];
        const size_t obase = ((size_t)b * kCout + o) * kL + l0 + wl + fq * 4;
        #pragma unroll
        for (int mi = 0; mi < 4; ++mi) {
            float4 st;
            float y0 = fmaxf(fmaf(accY[mi][ni][0], sc, sh), 0.f);
            float y1 = fmaxf(fmaf(accY[mi][ni][1], sc, sh), 0.f);
            float y2 = fmaxf(fmaf(accY[mi][ni][2], sc, sh), 0.f);
            float y3 = fmaxf(fmaf(accY[mi][ni][3], sc, sh), 0.f);
            st.x = fmaxf(y0 + accR[mi][ni][0] + rb, 0.f);
            st.y = fmaxf(y1 + accR[mi][ni][1] + rb, 0.f);
            st.z = fmaxf(y2 + accR[mi][ni][2] + rb, 0.f);
            st.w = fmaxf(y3 + accR[mi][ni][3] + rb, 0.f);
            *(float4*)&out[obase + mi * 16] = st;
        }
    }
}

extern "C" void kernel_launch(void* const* d_in, const int* in_sizes, int n_in,
                              void* d_out, int out_size, void* d_ws, size_t ws_size,
                              hipStream_t stream)
{
    (void)in_sizes; (void)n_in; (void)out_size;
    const float* x     = (const float*)d_in[0];
    const float* sw    = (const float*)d_in[1];
    const float* pw_w  = (const float*)d_in[2];
    const float* gamma = (const float*)d_in[4];
    const float* beta  = (const float*)d_in[5];
    const float* res_w = (const float*)d_in[6];
    const float* res_b = (const float*)d_in[7];
    float* out = (float*)d_out;
    float* wsf = (float*)d_ws;

    if (ws_size >= A_BYTES) {
        unsigned short* Wbf = (unsigned short*)(wsf + A_WBF);
        unsigned short* Zc  = (unsigned short*)(wsf + A_ZC);
        unsigned short* Zt  = (unsigned short*)(wsf + A_ZT);
        unsigned short* Xt  = (unsigned short*)(wsf + A_XT);
        unsigned* cnt = (unsigned*)(wsf + A_CNT);
        k_prep<<<1152, 256, 0, stream>>>(x, sw, pw_w, res_w, Zc, Zt, Xt, Wbf, cnt);
        k_mid<<<256, 256, 0, stream>>>(Zc, wsf + A_GPART, wsf + A_G, wsf + A_SZ,
                                       Wbf, gamma, beta, wsf + A_SC, wsf + A_SH, cnt);
        k_out3<<<GRID_OUT, 256, 0, stream>>>(Zt, Xt, Wbf, res_b,
                                             wsf + A_SC, wsf + A_SH, out);
    } else if (ws_size >= B_BYTES) {
        unsigned short* Wbf = (unsigned short*)(wsf + B_WBF);
        unsigned short* Zc  = (unsigned short*)(wsf + B_ZC);
        k_init<<<161, 256, 0, stream>>>(pw_w, res_w, Wbf, wsf + B_SZ, wsf + B_G);
        k_prepc<<<256 * 32, 256, 0, stream>>>(x, sw, Zc, wsf + B_SZ);
        k_gram2<<<256, 256, 0, stream>>>(Zc, wsf + B_GPART);
        k_gred<<<288, 256, 0, stream>>>(wsf + B_GPART, Zc, wsf + B_G, wsf + B_SZ);
        k_bnp<<<kCout, 256, 0, stream>>>(wsf + B_G, wsf + B_SZ, Wbf, gamma, beta,
                                         wsf + B_SC, wsf + B_SH);
        k_out2<<<GRID_OUT, 256, 0, stream>>>(x, sw, Wbf, res_b,
                                             wsf + B_SC, wsf + B_SH, out);
    } else {
        unsigned short* Wbf = (unsigned short*)(wsf + F_WBF);
        k_init<<<161, 256, 0, stream>>>(pw_w, res_w, Wbf, wsf + F_SZ, wsf + F_G);
        k_gram_fb<<<512, 256, 0, stream>>>(x, sw, wsf + F_G, wsf + F_SZ);
        k_bnp<<<kCout, 256, 0, stream>>>(wsf + F_G, wsf + F_SZ, Wbf, gamma, beta,
                                         wsf + F_SC, wsf + F_SH);
        k_out2<<<GRID_OUT, 256, 0, stream>>>(x, sw, Wbf, res_b,
                                             wsf + F_SC, wsf + F_SH, out);
    }
}

// Round 7
// 314.397 us; speedup vs baseline: 1.3205x; 1.3205x over previous
//
#include <hip/hip_runtime.h>

typedef __attribute__((ext_vector_type(8))) short short8;
typedef __attribute__((ext_vector_type(4))) float floatx4;

namespace {
constexpr int kB = 32, kCin = 256, kCout = 512, kL = 2048;
constexpr float kEps = 1e-5f;
constexpr float kInvN = 1.0f / (float)(kB * kL);   // 1/65536
constexpr int kKtot = kB * kL;                     // 65536
constexpr int BK = 32;
constexpr int KSTEPS = kCin / BK;                  // 8
constexpr int ST = 44;                             // padded LDS row stride (ushorts) for B tiles
constexpr int GRID_OUT = 4 * (kL / 128) * kB;      // 2048

// ---- main ws layout (float units): R1 pipeline, 51.1 MiB ----
constexpr size_t W_ZC    = 0;           // ushort Zc[256][65536]
constexpr size_t W_GPART = 8388608;     // float Gpart[256][16384]
constexpr size_t W_G     = 12582912;
constexpr size_t W_SZ    = 12648448;
constexpr size_t W_SC    = 12648704;
constexpr size_t W_SH    = 12649216;
constexpr size_t W_WBF   = 12649728;    // ushort Wbf[2][512][256]
constexpr size_t W_END   = 12780800;
constexpr size_t W_BYTES = W_END * 4ull;           // 51,123,200 B

// ---- fallback ws layout (floats) ----
constexpr size_t F_G = 0, F_SZ = 65536, F_SC = 65792, F_SH = 66304, F_WBF = 66816;
constexpr size_t F_END = 197888;
constexpr size_t F_BYTES = F_END * 4ull;
}

__device__ inline unsigned short f2bf(float f) {
    union { float f; unsigned u; } v; v.f = f;
    return (unsigned short)((v.u + 0x7fffu + ((v.u >> 16) & 1u)) >> 16);  // RNE
}
__device__ inline float bf2f(unsigned short h) {
    union { unsigned u; float f; } v; v.u = ((unsigned)h) << 16; return v.f;
}
__device__ inline unsigned pack2(float lo, float hi) {
    return (unsigned)f2bf(lo) | ((unsigned)f2bf(hi) << 16);
}
// single-instruction packed f32->bf16 (RNE), lo -> bits[15:0]
__device__ inline unsigned cvtpk(float lo, float hi) {
    unsigned r;
    asm("v_cvt_pk_bf16_f32 %0, %1, %2" : "=v"(r) : "v"(lo), "v"(hi));
    return r;
}
// async 16B global->LDS (lane i lands at wave-uniform lds_base + i*16)
__device__ inline void cp16(const void* g, void* l) {
    __builtin_amdgcn_global_load_lds(
        (const __attribute__((address_space(1))) unsigned int*)g,
        (__attribute__((address_space(3))) unsigned int*)l, 16, 0, 0);
}

// ============================================================ init: weights -> bf16, zero Sz + G
__global__ __launch_bounds__(256) void k_init(
    const float* __restrict__ pw_w, const float* __restrict__ res_w,
    unsigned short* __restrict__ Wbf, float* __restrict__ Sz, float* __restrict__ G)
{
    const int bid = blockIdx.x, tid = threadIdx.x;
    if (bid < 128) {
        const float* src = (bid < 64) ? pw_w : res_w;
        const int i = (bid & 63) * 2048 + tid * 8;
        float4 a = *(const float4*)(src + i);
        float4 b = *(const float4*)(src + i + 4);
        union { unsigned short u[8]; short8 v; } o;
        o.u[0]=f2bf(a.x); o.u[1]=f2bf(a.y); o.u[2]=f2bf(a.z); o.u[3]=f2bf(a.w);
        o.u[4]=f2bf(b.x); o.u[5]=f2bf(b.y); o.u[6]=f2bf(b.z); o.u[7]=f2bf(b.w);
        *(short8*)(Wbf + (bid < 64 ? 0 : 131072) + i) = o.v;
    } else if (bid == 128) {
        Sz[tid] = 0.f;
    } else {
        const int i = (bid - 129) * 2048 + tid * 8;
        float4 z4 = make_float4(0.f, 0.f, 0.f, 0.f);
        *(float4*)(G + i) = z4;
        *(float4*)(G + i + 4) = z4;
    }
}

// ============================================================ prep: x -> Zc bf16 [c][b*L], + Sz
__global__ __launch_bounds__(256, 4) void k_prepc(
    const float* __restrict__ x, const float* __restrict__ sw,
    unsigned short* __restrict__ Zc, float* __restrict__ Sz)
{
    __shared__ float wred[4];
    const int tid = threadIdx.x;
    const int lane = tid & 63, wave = tid >> 6;
    const int c = blockIdx.x >> 5;
    const int b = blockIdx.x & 31;
    const float w0 = sw[0], w1 = sw[1], w2 = sw[2];
    const int l = tid * 8;
    const float* xr = x + ((size_t)b * kCin + c) * kL + l;
    float4 c0 = *(const float4*)xr;
    float4 c1 = *(const float4*)(xr + 4);
    float4 pv = (l >= 4) ? *(const float4*)(xr - 4) : make_float4(0.f, 0.f, 0.f, 0.f);
    float V[12] = {pv.x,pv.y,pv.z,pv.w, c0.x,c0.y,c0.z,c0.w, c1.x,c1.y,c1.z,c1.w};
    union { unsigned short u[8]; short8 v; } o;
    float s = 0.f;
    #pragma unroll
    for (int j = 0; j < 8; ++j) {
        float z = fmaf(w0, V[j], fmaf(w1, V[j + 2], w2 * V[j + 4]));
        o.u[j] = f2bf(z);
        s += z;
    }
    *(short8*)(Zc + ((size_t)c << 16) + b * kL + l) = o.v;
    #pragma unroll
    for (int m = 1; m <= 32; m <<= 1) s += __shfl_xor(s, m, 64);
    if (lane == 0) wred[wave] = s;
    __syncthreads();
    if (tid == 0) atomicAdd(&Sz[c], (wred[0] + wred[1]) + (wred[2] + wred[3]));
}

// ============================================================ Gram GEMM (R1 form): double-buffered cp16,
// granule-swizzled LDS. 64 chunks x 1024k x 4 quads = 256 blocks.
__global__ __launch_bounds__(256, 2) void k_gram2(
    const unsigned short* __restrict__ Zc, float* __restrict__ Gpart)
{
    __shared__ __align__(16) unsigned short Zm[2][128 * 32];
    __shared__ __align__(16) unsigned short Zn[2][128 * 32];

    const int tid = threadIdx.x;
    const int lane = tid & 63, wave = tid >> 6;
    const int fr = lane & 15, fq = lane >> 4;
    const int q = blockIdx.x & 3;
    const int h = blockIdx.x >> 2;
    const int qm = (q >> 1) * 128, qn = (q & 1) * 128;
    const int wm = (wave >> 1) * 64, wn = (wave & 1) * 64;

    const int srow = wave * 32 + (lane >> 2);
    const int gsw = (((lane & 3) ^ ((lane >> 3) & 3)) * 8);
    const size_t kbase = (size_t)h * 1024 + gsw;
    const unsigned short* gm0 = Zc + (size_t)(qm + srow) * kKtot + kbase;
    const unsigned short* gm1 = gm0 + (size_t)16 * kKtot;
    const unsigned short* gn0 = Zc + (size_t)(qn + srow) * kKtot + kbase;
    const unsigned short* gn1 = gn0 + (size_t)16 * kKtot;

    unsigned short* zm0 = &Zm[0][wave * 1024];
    unsigned short* zm1 = &Zm[1][wave * 1024];
    unsigned short* zn0 = &Zn[0][wave * 1024];
    unsigned short* zn1 = &Zn[1][wave * 1024];

    const int rsw = (fr >> 1) & 3;
    int aoff[4], boff[4];
    #pragma unroll
    for (int mi = 0; mi < 4; ++mi) aoff[mi] = (wm + mi * 16 + fr) * 32 + ((fq ^ rsw) * 8);
    #pragma unroll
    for (int ni = 0; ni < 4; ++ni) boff[ni] = (wn + ni * 16 + fr) * 32 + ((fq ^ rsw) * 8);

    floatx4 acc[4][4];
    #pragma unroll
    for (int mi = 0; mi < 4; ++mi)
        #pragma unroll
        for (int ni = 0; ni < 4; ++ni) acc[mi][ni] = (floatx4){0.f, 0.f, 0.f, 0.f};

    auto STAGE = [&](unsigned short* m0, unsigned short* n0) {
        cp16(gm0, m0); cp16(gm1, m0 + 512);
        cp16(gn0, n0); cp16(gn1, n0 + 512);
        gm0 += 32; gm1 += 32; gn0 += 32; gn1 += 32;
    };

    STAGE(zm0, zn0);
    for (int t = 0; t < 32; ++t) {
        __syncthreads();
        if (t < 31) { if (t & 1) STAGE(zm0, zn0); else STAGE(zm1, zn1); }
        const unsigned short* rm = (t & 1) ? &Zm[1][0] : &Zm[0][0];
        const unsigned short* rn = (t & 1) ? &Zn[1][0] : &Zn[0][0];
        short8 bfp[4];
        #pragma unroll
        for (int ni = 0; ni < 4; ++ni)
            bfp[ni] = *(const short8*)&rn[boff[ni]];
        #pragma unroll
        for (int mi = 0; mi < 4; ++mi) {
            short8 af = *(const short8*)&rm[aoff[mi]];
            #pragma unroll
            for (int ni = 0; ni < 4; ++ni)
                acc[mi][ni] = __builtin_amdgcn_mfma_f32_16x16x32_bf16(af, bfp[ni], acc[mi][ni], 0, 0, 0);
        }
    }

    float* gp = Gpart + (size_t)blockIdx.x * 16384;
    #pragma unroll
    for (int mi = 0; mi < 4; ++mi)
        #pragma unroll
        for (int ni = 0; ni < 4; ++ni) {
            const int col = wn + ni * 16 + fr;
            #pragma unroll
            for (int r = 0; r < 4; ++r)
                gp[(wm + mi * 16 + fq * 4 + r) * 128 + col] = acc[mi][ni][r];
        }
}

// ============================================================ reduce Gpart -> G (R1 form)
__global__ __launch_bounds__(256) void k_gred(const float* __restrict__ Gpart, float* __restrict__ G)
{
    const int q = blockIdx.x >> 6;
    const int e = (blockIdx.x & 63) * 256 + threadIdx.x;
    const int qm = (q >> 1) * 128, qn = (q & 1) * 128;
    const float* p = Gpart + (size_t)q * 16384 + e;
    float s0 = 0.f, s1 = 0.f, s2 = 0.f, s3 = 0.f;
    #pragma unroll 4
    for (int hh = 0; hh < 64; hh += 4) {
        s0 += p[(size_t)(hh + 0) * 65536];
        s1 += p[(size_t)(hh + 1) * 65536];
        s2 += p[(size_t)(hh + 2) * 65536];
        s3 += p[(size_t)(hh + 3) * 65536];
    }
    G[(qm + (e >> 7)) * 256 + qn + (e & 127)] = (s0 + s1) + (s2 + s3);
}

// ============================================================ BN params (R1 form)
__global__ __launch_bounds__(256) void k_bnp(
    const float* __restrict__ G, const float* __restrict__ Sz,
    const unsigned short* __restrict__ Wbf, const float* __restrict__ gamma,
    const float* __restrict__ beta, float* __restrict__ sc_out, float* __restrict__ sh_out)
{
    __shared__ float t[256];
    __shared__ float redq[4], redm[4];
    const int o = blockIdx.x, c = threadIdx.x;
    const int lane = c & 63, wave = c >> 6;
    t[c] = bf2f(Wbf[(size_t)o * kCin + c]);
    __syncthreads();
    const float myt = t[c];
    float q0 = 0.f, q1 = 0.f, q2 = 0.f, q3 = 0.f;
    #pragma unroll 4
    for (int j = 0; j < 256; j += 4) {
        q0 = fmaf(t[j + 0], G[(j + 0) * 256 + c], q0);
        q1 = fmaf(t[j + 1], G[(j + 1) * 256 + c], q1);
        q2 = fmaf(t[j + 2], G[(j + 2) * 256 + c], q2);
        q3 = fmaf(t[j + 3], G[(j + 3) * 256 + c], q3);
    }
    float q = ((q0 + q1) + (q2 + q3)) * myt;
    float m = myt * Sz[c];
    #pragma unroll
    for (int off = 1; off <= 32; off <<= 1) {
        q += __shfl_xor(q, off, 64);
        m += __shfl_xor(m, off, 64);
    }
    if (lane == 0) { redq[wave] = q; redm[wave] = m; }
    __syncthreads();
    if (c == 0) {
        const float qt = (redq[0] + redq[1]) + (redq[2] + redq[3]);
        const float mt = (redm[0] + redm[1]) + (redm[2] + redm[3]);
        const float mean = mt * kInvN;
        const float var = qt * kInvN - mean * mean;
        const float s = gamma[o] * rsqrtf(var + kEps);
        sc_out[o] = s;
        sh_out[o] = fmaf(-mean, s, beta[o]);
    }
}

// ============================================================ fallback gram (VALU version)
__global__ __launch_bounds__(256, 2) void k_gram_fb(
    const float* __restrict__ x, const float* __restrict__ sw,
    float* __restrict__ G, float* __restrict__ Sz)
{
    __shared__ __align__(16) unsigned short Zt[256 * ST];
    const int tid = threadIdx.x;
    const int lane = tid & 63, wave = tid >> 6;
    const int fr = lane & 15, fq = lane >> 4;
    const int quad = blockIdx.x & 3;
    const int chunk = blockIdx.x >> 2;
    const int qm = (quad >> 1) * 128, qn = (quad & 1) * 128;
    const int b = chunk >> 2;
    const int l0 = (chunk & 3) * 512;
    const bool dosz = (quad == 0);
    const float w0 = sw[0], w1 = sw[1], w2 = sw[2];
    const float* xb = x + (size_t)b * kCin * kL;

    floatx4 acc[4][4];
    #pragma unroll
    for (int mi = 0; mi < 4; ++mi)
        #pragma unroll
        for (int ni = 0; ni < 4; ++ni) acc[mi][ni] = (floatx4){0.f, 0.f, 0.f, 0.f};

    const int cr = tid >> 3;
    const int loff = (tid & 7) * 4;
    float sz[8] = {0.f,0.f,0.f,0.f,0.f,0.f,0.f,0.f};
    int aOff[4], bOff[4];
    #pragma unroll
    for (int mi = 0; mi < 4; ++mi) aOff[mi] = (qm + (wave >> 1) * 64 + mi * 16 + fr) * ST + fq * 8;
    #pragma unroll
    for (int ni = 0; ni < 4; ++ni) bOff[ni] = (qn + (wave & 1) * 64 + ni * 16 + fr) * ST + fq * 8;

    for (int ks = 0; ks < 16; ++ks) {
        const int lk = l0 + ks * BK;
        const bool hasprv = (lk + loff) >= 4;
        __syncthreads();
        #pragma unroll
        for (int p = 0; p < 8; ++p) {
            const int c = p * 32 + cr;
            const float* bp = xb + (size_t)c * kL + lk + loff;
            float4 cur = *(const float4*)bp;
            float4 prv = hasprv ? *(const float4*)(bp - 4) : make_float4(0.f,0.f,0.f,0.f);
            float z0 = fmaf(w0, prv.x, fmaf(w1, prv.z, w2 * cur.x));
            float z1 = fmaf(w0, prv.y, fmaf(w1, prv.w, w2 * cur.y));
            float z2 = fmaf(w0, prv.z, fmaf(w1, cur.x, w2 * cur.z));
            float z3 = fmaf(w0, prv.w, fmaf(w1, cur.y, w2 * cur.w));
            *(unsigned*)&Zt[c * ST + loff]     = pack2(z0, z1);
            *(unsigned*)&Zt[c * ST + loff + 2] = pack2(z2, z3);
            if (dosz) sz[p] += (z0 + z1) + (z2 + z3);
        }
        __syncthreads();
        short8 bf_[4];
        #pragma unroll
        for (int ni = 0; ni < 4; ++ni) bf_[ni] = *(const short8*)&Zt[bOff[ni]];
        #pragma unroll
        for (int mi = 0; mi < 4; ++mi) {
            short8 af = *(const short8*)&Zt[aOff[mi]];
            #pragma unroll
            for (int ni = 0; ni < 4; ++ni)
                acc[mi][ni] = __builtin_amdgcn_mfma_f32_16x16x32_bf16(af, bf_[ni], acc[mi][ni], 0, 0, 0);
        }
    }
    #pragma unroll
    for (int mi = 0; mi < 4; ++mi) {
        const int growb = qm + (wave >> 1) * 64 + mi * 16 + fq * 4;
        #pragma unroll
        for (int ni = 0; ni < 4; ++ni) {
            const int gcol = qn + (wave & 1) * 64 + ni * 16 + fr;
            #pragma unroll
            for (int r = 0; r < 4; ++r)
                atomicAdd(&G[(growb + r) * 256 + gcol], acc[mi][ni][r]);
        }
    }
    if (dosz) {
        #pragma unroll
        for (int p = 0; p < 8; ++p) {
            float s = sz[p];
            s += __shfl_xor(s, 1, 64);
            s += __shfl_xor(s, 2, 64);
            s += __shfl_xor(s, 4, 64);
            if ((lane & 7) == 0) atomicAdd(&Sz[p * 32 + cr], s);
        }
    }
}

// ============================================================ output: U-reformulated dual GEMM.
// U = Wp.x, R = Wr.x share one B-operand (raw x, no conv in pack). Y built in epilogue:
// Y[o,l] = w0*U[o,l-4] + w1*U[o,l-2] + w2*U[o,l] via intra-16-lane shuffles + halo fragment.
__global__ __launch_bounds__(256, 2) void k_out4(
    const float* __restrict__ x, const float* __restrict__ sw,
    const unsigned short* __restrict__ Wbf,
    const float* __restrict__ res_b, const float* __restrict__ sc_arr,
    const float* __restrict__ sh_arr, float* __restrict__ out)
{
    __shared__ __align__(16) unsigned short As[2 * 128 * 32];  // [Wp|Wr][o row][32c] swizzled granules
    __shared__ __align__(16) unsigned short Bx[144 * ST];      // rows: l0-16 .. l0+127 (idx = l-l0+16)

    const int tid = threadIdx.x;
    const int lane = tid & 63, wave = tid >> 6;
    const int fr = lane & 15, fq = lane >> 4;
    const int wo = (wave >> 1) * 64;
    const int wl = (wave & 1) * 64;

    // XCD-grouped decode (4 o-tile blocks sharing an x-slice adjacent on one XCD)
    const int pid = blockIdx.x;
    const int slot = pid >> 3;
    const int mt = slot & 3;
    const int u = (pid & 7) * 64 + (slot >> 2);
    const int lt = u & 15;
    const int b = u >> 4;
    const int o0 = mt * 128, l0 = lt * 128;

    const float w0 = sw[0], w1 = sw[1], w2 = sw[2];
    const float* xb = x + (size_t)b * kCin * kL;

    floatx4 accY[4][4], accR[4][4], accH[4];
    #pragma unroll
    for (int mi = 0; mi < 4; ++mi) {
        accH[mi] = (floatx4){0.f, 0.f, 0.f, 0.f};
        #pragma unroll
        for (int ni = 0; ni < 4; ++ni) {
            accY[mi][ni] = (floatx4){0.f, 0.f, 0.f, 0.f};
            accR[mi][ni] = (floatx4){0.f, 0.f, 0.f, 0.f};
        }
    }

    // ---- A staging: 4 cp16/thread/kstep, linear LDS dest + XOR'd global source granule ----
    const int gsw = (((lane & 3) ^ ((lane >> 3) & 3)) * 8);
    const unsigned short* wsrc[4];
    unsigned short* wdst[4];
    #pragma unroll
    for (int j = 0; j < 4; ++j) {
        const int m = j >> 1;
        const int r = (j & 1) * 64 + wave * 16 + (lane >> 2);
        wsrc[j] = Wbf + (size_t)m * 131072 + (size_t)(o0 + r) * kCin + gsw;
        wdst[j] = As + j * 2048 + wave * 512;
    }

    // ---- fragment read offsets ----
    const int rsw = (fr >> 1) & 3;
    int aOffP[4], bOff[4];
    #pragma unroll
    for (int mi = 0; mi < 4; ++mi)
        aOffP[mi] = (wo + mi * 16 + fr) * 32 + ((fq ^ rsw) * 8);
    #pragma unroll
    for (int ni = 0; ni < 4; ++ni) bOff[ni] = (16 + wl + ni * 16 + fr) * ST + fq * 8;
    const int bOffH = (wl + fr) * ST + fq * 8;     // halo frag: 16 l below this wave's range

    // ---- B load/pack: 2 c-rows x 8 l main + 1 halo value x 2 c ----
    const int c2 = (tid & 15) * 2;
    const int ll = (tid >> 4) * 8;
    const int hr = tid >> 4;                       // halo row 0..15
    const bool hok = (l0 > 0);
    const int lh = hok ? (l0 - 16 + hr) : 0;
    float4 xa0, xa1, xb0, xb1;
    float xh0, xh1;
    auto LOAD = [&](int ks) {
        const int k0 = ks * BK;
        const float* base0 = xb + (size_t)(k0 + c2) * kL + l0 + ll;
        const float* base1 = base0 + kL;
        xa0 = *(const float4*)(base0);
        xa1 = *(const float4*)(base0 + 4);
        xb0 = *(const float4*)(base1);
        xb1 = *(const float4*)(base1 + 4);
        const float* hbase = xb + (size_t)(k0 + c2) * kL + lh;
        xh0 = hbase[0];
        xh1 = hbase[kL];
    };
    auto PACKB = [&]() {
        float A[8]  = {xa0.x,xa0.y,xa0.z,xa0.w, xa1.x,xa1.y,xa1.z,xa1.w};
        float Bv[8] = {xb0.x,xb0.y,xb0.z,xb0.w, xb1.x,xb1.y,xb1.z,xb1.w};
        #pragma unroll
        for (int j = 0; j < 8; ++j)
            *(unsigned*)&Bx[(16 + ll + j) * ST + c2] = cvtpk(A[j], Bv[j]);
        unsigned hv = hok ? cvtpk(xh0, xh1) : 0u;
        *(unsigned*)&Bx[hr * ST + c2] = hv;
    };

    LOAD(0);
    for (int ks = 0; ks < KSTEPS; ++ks) {
        #pragma unroll
        for (int j = 0; j < 4; ++j) { cp16(wsrc[j], wdst[j]); wsrc[j] += BK; }
        PACKB();
        __syncthreads();                     // drains cp16 (vmcnt) + B ds_writes (lgkm)
        if (ks < KSTEPS - 1) LOAD(ks + 1);   // prefetch next x slice under MFMA phase
        short8 vx[4];
        short8 vh = *(const short8*)&Bx[bOffH];
        #pragma unroll
        for (int ni = 0; ni < 4; ++ni)
            vx[ni] = *(const short8*)&Bx[bOff[ni]];
        #pragma unroll
        for (int mi = 0; mi < 4; ++mi) {
            short8 ap = *(const short8*)&As[aOffP[mi]];
            short8 ar = *(const short8*)&As[4096 + aOffP[mi]];
            accH[mi] = __builtin_amdgcn_mfma_f32_16x16x32_bf16(ap, vh, accH[mi], 0, 0, 0);
            #pragma unroll
            for (int ni = 0; ni < 4; ++ni) {
                accY[mi][ni] = __builtin_amdgcn_mfma_f32_16x16x32_bf16(ap, vx[ni], accY[mi][ni], 0, 0, 0);
                accR[mi][ni] = __builtin_amdgcn_mfma_f32_16x16x32_bf16(ar, vx[ni], accR[mi][ni], 0, 0, 0);
            }
        }
        __syncthreads();                     // protect As/Bx reuse
    }

    // ---- epilogue: depthwise combine of U across l via shuffles, then BN+relu + residual ----
    const int s2 = (lane & 48) | ((fr - 2) & 15);
    const int s4 = (lane & 48) | ((fr - 4) & 15);
    #pragma unroll
    for (int mi = 0; mi < 4; ++mi)
        #pragma unroll
        for (int r = 0; r < 4; ++r) {
            const int o = o0 + wo + mi * 16 + fq * 4 + r;
            const float sc = sc_arr[o], sh = sh_arr[o], rb = res_b[o];
            const size_t orow = ((size_t)b * kCout + o) * kL + l0 + wl;
            float prev = accH[mi][r];
            #pragma unroll
            for (int ni = 0; ni < 4; ++ni) {
                const float cur = accY[mi][ni][r];
                const float c2v = __shfl(cur, s2, 64);
                const float p2v = __shfl(prev, s2, 64);
                const float c4v = __shfl(cur, s4, 64);
                const float p4v = __shfl(prev, s4, 64);
                const float um2 = (fr >= 2) ? c2v : p2v;
                const float um4 = (fr >= 4) ? c4v : p4v;
                const float yv = fmaf(w0, um4, fmaf(w1, um2, w2 * cur));
                const float yn = fmaxf(fmaf(yv, sc, sh), 0.f);
                const float rr = accR[mi][ni][r] + rb;
                out[orow + ni * 16 + fr] = fmaxf(yn + rr, 0.f);
                prev = cur;
            }
        }
}

extern "C" void kernel_launch(void* const* d_in, const int* in_sizes, int n_in,
                              void* d_out, int out_size, void* d_ws, size_t ws_size,
                              hipStream_t stream)
{
    (void)in_sizes; (void)n_in; (void)out_size;
    const float* x     = (const float*)d_in[0];
    const float* sw    = (const float*)d_in[1];
    const float* pw_w  = (const float*)d_in[2];
    const float* gamma = (const float*)d_in[4];
    const float* beta  = (const float*)d_in[5];
    const float* res_w = (const float*)d_in[6];
    const float* res_b = (const float*)d_in[7];
    float* out = (float*)d_out;
    float* wsf = (float*)d_ws;

    if (ws_size >= W_BYTES) {
        unsigned short* Wbf = (unsigned short*)(wsf + W_WBF);
        unsigned short* Zc  = (unsigned short*)(wsf + W_ZC);
        k_init<<<161, 256, 0, stream>>>(pw_w, res_w, Wbf, wsf + W_SZ, wsf + W_G);
        k_prepc<<<256 * 32, 256, 0, stream>>>(x, sw, Zc, wsf + W_SZ);
        k_gram2<<<256, 256, 0, stream>>>(Zc, wsf + W_GPART);
        k_gred<<<256, 256, 0, stream>>>(wsf + W_GPART, wsf + W_G);
        k_bnp<<<kCout, 256, 0, stream>>>(wsf + W_G, wsf + W_SZ, Wbf, gamma, beta,
                                         wsf + W_SC, wsf + W_SH);
        k_out4<<<GRID_OUT, 256, 0, stream>>>(x, sw, Wbf, res_b,
                                             wsf + W_SC, wsf + W_SH, out);
    } else {
        unsigned short* Wbf = (unsigned short*)(wsf + F_WBF);
        k_init<<<161, 256, 0, stream>>>(pw_w, res_w, Wbf, wsf + F_SZ, wsf + F_G);
        k_gram_fb<<<512, 256, 0, stream>>>(x, sw, wsf + F_G, wsf + F_SZ);
        k_bnp<<<kCout, 256, 0, stream>>>(wsf + F_G, wsf + F_SZ, Wbf, gamma, beta,
                                         wsf + F_SC, wsf + F_SH);
        k_out4<<<GRID_OUT, 256, 0, stream>>>(x, sw, Wbf, res_b,
                                             wsf + F_SC, wsf + F_SH, out);
    }
}

// Round 8
// 292.858 us; speedup vs baseline: 1.4176x; 1.0735x over previous
//
#include <hip/hip_runtime.h>

typedef __attribute__((ext_vector_type(8))) short short8;
typedef __attribute__((ext_vector_type(4))) float floatx4;

namespace {
constexpr int kB = 32, kCin = 256, kCout = 512, kL = 2048;
constexpr float kEps = 1e-5f;
constexpr float kInvN = 1.0f / (float)(kB * kL);   // 1/65536
constexpr int kKtot = kB * kL;                     // 65536
constexpr int BK = 32;
constexpr int KSTEPS = kCin / BK;                  // 8
constexpr int ST = 44;                             // padded LDS row stride (ushorts) for B tiles
constexpr int GRID_OUT = 4 * (kL / 128) * kB;      // 2048

// ---- main ws layout (float units): 34.4 MiB (Gpart removed; G accumulated via atomics) ----
constexpr size_t W_ZC    = 0;           // ushort Zc[256][65536] -> 8,388,608 floats
constexpr size_t W_G     = 8388608;     // float G[256*256]
constexpr size_t W_SZP   = 8454144;     // float Sz_part[256][32]
constexpr size_t W_SC    = 8462336;     // float sc[512]
constexpr size_t W_SH    = 8462848;     // float sh[512]
constexpr size_t W_WBF   = 8463360;     // ushort Wbf[2][512][256] -> 131,072 floats
constexpr size_t W_END   = 8594432;
constexpr size_t W_BYTES = W_END * 4ull;           // 34,377,728 B

// ---- fallback ws layout (floats) ----
constexpr size_t F_G = 0, F_SZ = 65536, F_SC = 65792, F_SH = 66304, F_WBF = 66816;
constexpr size_t F_END = 197888;
constexpr size_t F_BYTES = F_END * 4ull;
}

__device__ inline unsigned short f2bf(float f) {
    union { float f; unsigned u; } v; v.f = f;
    return (unsigned short)((v.u + 0x7fffu + ((v.u >> 16) & 1u)) >> 16);  // RNE
}
__device__ inline float bf2f(unsigned short h) {
    union { unsigned u; float f; } v; v.u = ((unsigned)h) << 16; return v.f;
}
__device__ inline unsigned pack2(float lo, float hi) {
    return (unsigned)f2bf(lo) | ((unsigned)f2bf(hi) << 16);
}
// single-instruction packed f32->bf16 (RNE), lo -> bits[15:0]
__device__ inline unsigned cvtpk(float lo, float hi) {
    unsigned r;
    asm("v_cvt_pk_bf16_f32 %0, %1, %2" : "=v"(r) : "v"(lo), "v"(hi));
    return r;
}
// async 16B global->LDS (lane i lands at wave-uniform lds_base + i*16)
__device__ inline void cp16(const void* g, void* l) {
    __builtin_amdgcn_global_load_lds(
        (const __attribute__((address_space(1))) unsigned int*)g,
        (__attribute__((address_space(3))) unsigned int*)l, 16, 0, 0);
}

// ============================================================ merged prep: x -> Zc bf16 + Sz_part,
// weights -> bf16, zero G. 8192 data blocks + 128 weight blocks + 32 G-zero blocks = 8352.
// Race-free: Sz_part is direct-store (no atomics); G atomics happen in the NEXT launch.
__global__ __launch_bounds__(256, 4) void k_prep(
    const float* __restrict__ x, const float* __restrict__ sw,
    const float* __restrict__ pw_w, const float* __restrict__ res_w,
    unsigned short* __restrict__ Zc, float* __restrict__ Szp,
    unsigned short* __restrict__ Wbf, float* __restrict__ G)
{
    const int bid = blockIdx.x, tid = threadIdx.x;
    if (bid >= 8192) {
        const int e = bid - 8192;
        if (e < 128) {                       // ---- weight conversion ----
            const float* src = (e < 64) ? pw_w : res_w;
            const int i = (e & 63) * 2048 + tid * 8;
            float4 a = *(const float4*)(src + i);
            float4 b = *(const float4*)(src + i + 4);
            uint4 o;
            o.x = cvtpk(a.x, a.y); o.y = cvtpk(a.z, a.w);
            o.z = cvtpk(b.x, b.y); o.w = cvtpk(b.z, b.w);
            *(uint4*)(Wbf + (e < 64 ? 0 : 131072) + i) = o;
        } else {                             // ---- zero G (32 blocks x 2048 floats) ----
            const int i = (e - 128) * 2048 + tid * 8;
            float4 z4 = make_float4(0.f, 0.f, 0.f, 0.f);
            *(float4*)(G + i) = z4;
            *(float4*)(G + i + 4) = z4;
        }
        return;
    }
    __shared__ float wred[4];
    const int lane = tid & 63, wave = tid >> 6;
    const int c = bid >> 5;                  // 0..255
    const int b = bid & 31;                  // 0..31
    const float w0 = sw[0], w1 = sw[1], w2 = sw[2];
    const int l = tid * 8;
    const float* xr = x + ((size_t)b * kCin + c) * kL + l;
    float4 c0 = *(const float4*)xr;
    float4 c1 = *(const float4*)(xr + 4);
    float4 pv = (l >= 4) ? *(const float4*)(xr - 4) : make_float4(0.f, 0.f, 0.f, 0.f);
    float V[12] = {pv.x,pv.y,pv.z,pv.w, c0.x,c0.y,c0.z,c0.w, c1.x,c1.y,c1.z,c1.w};
    union { unsigned short u[8]; short8 v; } o;
    float s = 0.f;
    #pragma unroll
    for (int j = 0; j < 8; ++j) {
        float z = fmaf(w0, V[j], fmaf(w1, V[j + 2], w2 * V[j + 4]));
        o.u[j] = f2bf(z);
        s += z;
    }
    *(short8*)(Zc + ((size_t)c << 16) + b * kL + l) = o.v;
    #pragma unroll
    for (int m = 1; m <= 32; m <<= 1) s += __shfl_xor(s, m, 64);
    if (lane == 0) wred[wave] = s;
    __syncthreads();
    if (tid == 0) Szp[c * 32 + b] = (wred[0] + wred[1]) + (wred[2] + wred[3]);
}

// ============================================================ Gram GEMM -> G directly via atomics.
// 64 h-chunks x 1024k x 4 quads = 256 blocks; 64 adds/cell, 65K distinct addresses.
__global__ __launch_bounds__(256, 2) void k_gramA(
    const unsigned short* __restrict__ Zc, float* __restrict__ G)
{
    __shared__ __align__(16) unsigned short Zm[2][128 * 32];
    __shared__ __align__(16) unsigned short Zn[2][128 * 32];

    const int tid = threadIdx.x;
    const int lane = tid & 63, wave = tid >> 6;
    const int fr = lane & 15, fq = lane >> 4;
    const int q = blockIdx.x & 3;
    const int h = blockIdx.x >> 2;
    const int qm = (q >> 1) * 128, qn = (q & 1) * 128;
    const int wm = (wave >> 1) * 64, wn = (wave & 1) * 64;

    const int srow = wave * 32 + (lane >> 2);
    const int gsw = (((lane & 3) ^ ((lane >> 3) & 3)) * 8);
    const size_t kbase = (size_t)h * 1024 + gsw;
    const unsigned short* gm0 = Zc + (size_t)(qm + srow) * kKtot + kbase;
    const unsigned short* gm1 = gm0 + (size_t)16 * kKtot;
    const unsigned short* gn0 = Zc + (size_t)(qn + srow) * kKtot + kbase;
    const unsigned short* gn1 = gn0 + (size_t)16 * kKtot;

    unsigned short* zm0 = &Zm[0][wave * 1024];
    unsigned short* zm1 = &Zm[1][wave * 1024];
    unsigned short* zn0 = &Zn[0][wave * 1024];
    unsigned short* zn1 = &Zn[1][wave * 1024];

    const int rsw = (fr >> 1) & 3;
    int aoff[4], boff[4];
    #pragma unroll
    for (int mi = 0; mi < 4; ++mi) aoff[mi] = (wm + mi * 16 + fr) * 32 + ((fq ^ rsw) * 8);
    #pragma unroll
    for (int ni = 0; ni < 4; ++ni) boff[ni] = (wn + ni * 16 + fr) * 32 + ((fq ^ rsw) * 8);

    floatx4 acc[4][4];
    #pragma unroll
    for (int mi = 0; mi < 4; ++mi)
        #pragma unroll
        for (int ni = 0; ni < 4; ++ni) acc[mi][ni] = (floatx4){0.f, 0.f, 0.f, 0.f};

    auto STAGE = [&](unsigned short* m0, unsigned short* n0) {
        cp16(gm0, m0); cp16(gm1, m0 + 512);
        cp16(gn0, n0); cp16(gn1, n0 + 512);
        gm0 += 32; gm1 += 32; gn0 += 32; gn1 += 32;
    };

    STAGE(zm0, zn0);
    for (int t = 0; t < 32; ++t) {
        __syncthreads();
        if (t < 31) { if (t & 1) STAGE(zm0, zn0); else STAGE(zm1, zn1); }
        const unsigned short* rm = (t & 1) ? &Zm[1][0] : &Zm[0][0];
        const unsigned short* rn = (t & 1) ? &Zn[1][0] : &Zn[0][0];
        short8 bfp[4];
        #pragma unroll
        for (int ni = 0; ni < 4; ++ni)
            bfp[ni] = *(const short8*)&rn[boff[ni]];
        #pragma unroll
        for (int mi = 0; mi < 4; ++mi) {
            short8 af = *(const short8*)&rm[aoff[mi]];
            #pragma unroll
            for (int ni = 0; ni < 4; ++ni)
                acc[mi][ni] = __builtin_amdgcn_mfma_f32_16x16x32_bf16(af, bfp[ni], acc[mi][ni], 0, 0, 0);
        }
    }

    #pragma unroll
    for (int mi = 0; mi < 4; ++mi)
        #pragma unroll
        for (int ni = 0; ni < 4; ++ni) {
            const int col = qn + wn + ni * 16 + fr;
            #pragma unroll
            for (int r = 0; r < 4; ++r) {
                const int row = qm + wm + mi * 16 + fq * 4 + r;
                atomicAdd(&G[row * 256 + col], acc[mi][ni][r]);
            }
        }
}

// ============================================================ BN params (Sz_part reduced inline)
__global__ __launch_bounds__(256) void k_bnp2(
    const float* __restrict__ G, const float* __restrict__ Szp,
    const unsigned short* __restrict__ Wbf, const float* __restrict__ gamma,
    const float* __restrict__ beta, float* __restrict__ sc_out, float* __restrict__ sh_out)
{
    __shared__ float t[256];
    __shared__ float redq[4], redm[4];
    const int o = blockIdx.x, c = threadIdx.x;
    const int lane = c & 63, wave = c >> 6;
    t[c] = bf2f(Wbf[(size_t)o * kCin + c]);
    float sz = 0.f;
    {
        const float* sp = Szp + c * 32;
        #pragma unroll 8
        for (int b2 = 0; b2 < 32; ++b2) sz += sp[b2];
    }
    __syncthreads();
    const float myt = t[c];
    float q0 = 0.f, q1 = 0.f, q2 = 0.f, q3 = 0.f;
    #pragma unroll 4
    for (int j = 0; j < 256; j += 4) {
        q0 = fmaf(t[j + 0], G[(j + 0) * 256 + c], q0);
        q1 = fmaf(t[j + 1], G[(j + 1) * 256 + c], q1);
        q2 = fmaf(t[j + 2], G[(j + 2) * 256 + c], q2);
        q3 = fmaf(t[j + 3], G[(j + 3) * 256 + c], q3);
    }
    float q = ((q0 + q1) + (q2 + q3)) * myt;
    float m = myt * sz;
    #pragma unroll
    for (int off = 1; off <= 32; off <<= 1) {
        q += __shfl_xor(q, off, 64);
        m += __shfl_xor(m, off, 64);
    }
    if (lane == 0) { redq[wave] = q; redm[wave] = m; }
    __syncthreads();
    if (c == 0) {
        const float qt = (redq[0] + redq[1]) + (redq[2] + redq[3]);
        const float mt = (redm[0] + redm[1]) + (redm[2] + redm[3]);
        const float mean = mt * kInvN;
        const float var = qt * kInvN - mean * mean;
        const float s = gamma[o] * rsqrtf(var + kEps);
        sc_out[o] = s;
        sh_out[o] = fmaf(-mean, s, beta[o]);
    }
}

// ============================================================ fallback init (F tier only)
__global__ __launch_bounds__(256) void k_init(
    const float* __restrict__ pw_w, const float* __restrict__ res_w,
    unsigned short* __restrict__ Wbf, float* __restrict__ Sz, float* __restrict__ G)
{
    const int bid = blockIdx.x, tid = threadIdx.x;
    if (bid < 128) {
        const float* src = (bid < 64) ? pw_w : res_w;
        const int i = (bid & 63) * 2048 + tid * 8;
        float4 a = *(const float4*)(src + i);
        float4 b = *(const float4*)(src + i + 4);
        uint4 o;
        o.x = cvtpk(a.x, a.y); o.y = cvtpk(a.z, a.w);
        o.z = cvtpk(b.x, b.y); o.w = cvtpk(b.z, b.w);
        *(uint4*)(Wbf + (bid < 64 ? 0 : 131072) + i) = o;
    } else if (bid == 128) {
        Sz[tid] = 0.f;
    } else {
        const int i = (bid - 129) * 2048 + tid * 8;
        float4 z4 = make_float4(0.f, 0.f, 0.f, 0.f);
        *(float4*)(G + i) = z4;
        *(float4*)(G + i + 4) = z4;
    }
}

// ============================================================ fallback BN params (reads Sz directly)
__global__ __launch_bounds__(256) void k_bnp(
    const float* __restrict__ G, const float* __restrict__ Sz,
    const unsigned short* __restrict__ Wbf, const float* __restrict__ gamma,
    const float* __restrict__ beta, float* __restrict__ sc_out, float* __restrict__ sh_out)
{
    __shared__ float t[256];
    __shared__ float redq[4], redm[4];
    const int o = blockIdx.x, c = threadIdx.x;
    const int lane = c & 63, wave = c >> 6;
    t[c] = bf2f(Wbf[(size_t)o * kCin + c]);
    __syncthreads();
    const float myt = t[c];
    float q0 = 0.f, q1 = 0.f, q2 = 0.f, q3 = 0.f;
    #pragma unroll 4
    for (int j = 0; j < 256; j += 4) {
        q0 = fmaf(t[j + 0], G[(j + 0) * 256 + c], q0);
        q1 = fmaf(t[j + 1], G[(j + 1) * 256 + c], q1);
        q2 = fmaf(t[j + 2], G[(j + 2) * 256 + c], q2);
        q3 = fmaf(t[j + 3], G[(j + 3) * 256 + c], q3);
    }
    float q = ((q0 + q1) + (q2 + q3)) * myt;
    float m = myt * Sz[c];
    #pragma unroll
    for (int off = 1; off <= 32; off <<= 1) {
        q += __shfl_xor(q, off, 64);
        m += __shfl_xor(m, off, 64);
    }
    if (lane == 0) { redq[wave] = q; redm[wave] = m; }
    __syncthreads();
    if (c == 0) {
        const float qt = (redq[0] + redq[1]) + (redq[2] + redq[3]);
        const float mt = (redm[0] + redm[1]) + (redm[2] + redm[3]);
        const float mean = mt * kInvN;
        const float var = qt * kInvN - mean * mean;
        const float s = gamma[o] * rsqrtf(var + kEps);
        sc_out[o] = s;
        sh_out[o] = fmaf(-mean, s, beta[o]);
    }
}

// ============================================================ fallback gram (VALU version)
__global__ __launch_bounds__(256, 2) void k_gram_fb(
    const float* __restrict__ x, const float* __restrict__ sw,
    float* __restrict__ G, float* __restrict__ Sz)
{
    __shared__ __align__(16) unsigned short Zt[256 * ST];
    const int tid = threadIdx.x;
    const int lane = tid & 63, wave = tid >> 6;
    const int fr = lane & 15, fq = lane >> 4;
    const int quad = blockIdx.x & 3;
    const int chunk = blockIdx.x >> 2;
    const int qm = (quad >> 1) * 128, qn = (quad & 1) * 128;
    const int b = chunk >> 2;
    const int l0 = (chunk & 3) * 512;
    const bool dosz = (quad == 0);
    const float w0 = sw[0], w1 = sw[1], w2 = sw[2];
    const float* xb = x + (size_t)b * kCin * kL;

    floatx4 acc[4][4];
    #pragma unroll
    for (int mi = 0; mi < 4; ++mi)
        #pragma unroll
        for (int ni = 0; ni < 4; ++ni) acc[mi][ni] = (floatx4){0.f, 0.f, 0.f, 0.f};

    const int cr = tid >> 3;
    const int loff = (tid & 7) * 4;
    float sz[8] = {0.f,0.f,0.f,0.f,0.f,0.f,0.f,0.f};
    int aOff[4], bOff[4];
    #pragma unroll
    for (int mi = 0; mi < 4; ++mi) aOff[mi] = (qm + (wave >> 1) * 64 + mi * 16 + fr) * ST + fq * 8;
    #pragma unroll
    for (int ni = 0; ni < 4; ++ni) bOff[ni] = (qn + (wave & 1) * 64 + ni * 16 + fr) * ST + fq * 8;

    for (int ks = 0; ks < 16; ++ks) {
        const int lk = l0 + ks * BK;
        const bool hasprv = (lk + loff) >= 4;
        __syncthreads();
        #pragma unroll
        for (int p = 0; p < 8; ++p) {
            const int c = p * 32 + cr;
            const float* bp = xb + (size_t)c * kL + lk + loff;
            float4 cur = *(const float4*)bp;
            float4 prv = hasprv ? *(const float4*)(bp - 4) : make_float4(0.f,0.f,0.f,0.f);
            float z0 = fmaf(w0, prv.x, fmaf(w1, prv.z, w2 * cur.x));
            float z1 = fmaf(w0, prv.y, fmaf(w1, prv.w, w2 * cur.y));
            float z2 = fmaf(w0, prv.z, fmaf(w1, cur.x, w2 * cur.z));
            float z3 = fmaf(w0, prv.w, fmaf(w1, cur.y, w2 * cur.w));
            *(unsigned*)&Zt[c * ST + loff]     = pack2(z0, z1);
            *(unsigned*)&Zt[c * ST + loff + 2] = pack2(z2, z3);
            if (dosz) sz[p] += (z0 + z1) + (z2 + z3);
        }
        __syncthreads();
        short8 bf_[4];
        #pragma unroll
        for (int ni = 0; ni < 4; ++ni) bf_[ni] = *(const short8*)&Zt[bOff[ni]];
        #pragma unroll
        for (int mi = 0; mi < 4; ++mi) {
            short8 af = *(const short8*)&Zt[aOff[mi]];
            #pragma unroll
            for (int ni = 0; ni < 4; ++ni)
                acc[mi][ni] = __builtin_amdgcn_mfma_f32_16x16x32_bf16(af, bf_[ni], acc[mi][ni], 0, 0, 0);
        }
    }
    #pragma unroll
    for (int mi = 0; mi < 4; ++mi) {
        const int growb = qm + (wave >> 1) * 64 + mi * 16 + fq * 4;
        #pragma unroll
        for (int ni = 0; ni < 4; ++ni) {
            const int gcol = qn + (wave & 1) * 64 + ni * 16 + fr;
            #pragma unroll
            for (int r = 0; r < 4; ++r)
                atomicAdd(&G[(growb + r) * 256 + gcol], acc[mi][ni][r]);
        }
    }
    if (dosz) {
        #pragma unroll
        for (int p = 0; p < 8; ++p) {
            float s = sz[p];
            s += __shfl_xor(s, 1, 64);
            s += __shfl_xor(s, 2, 64);
            s += __shfl_xor(s, 4, 64);
            if ((lane & 7) == 0) atomicAdd(&Sz[p * 32 + cr], s);
        }
    }
}

// ============================================================ output: 128x128 dual GEMM (R1 version,
// best measured: 84.7 us). Register-prefetch x, cp16 weights, XCD-grouped blocks.
__global__ __launch_bounds__(256, 2) void k_out2(
    const float* __restrict__ x, const float* __restrict__ sw,
    const unsigned short* __restrict__ Wbf,
    const float* __restrict__ res_b, const float* __restrict__ sc_arr,
    const float* __restrict__ sh_arr, float* __restrict__ out)
{
    __shared__ __align__(16) unsigned short As[2 * 128 * 32];
    __shared__ __align__(16) unsigned short Bz[128 * ST];
    __shared__ __align__(16) unsigned short Bx[128 * ST];

    const int tid = threadIdx.x;
    const int lane = tid & 63, wave = tid >> 6;
    const int fr = lane & 15, fq = lane >> 4;
    const int wo = (wave >> 1) * 64;
    const int wl = (wave & 1) * 64;

    const int pid = blockIdx.x;
    const int slot = pid >> 3;
    const int mt = slot & 3;
    const int u = (pid & 7) * 64 + (slot >> 2);
    const int lt = u & 15;
    const int b = u >> 4;
    const int o0 = mt * 128, l0 = lt * 128;

    const float w0 = sw[0], w1 = sw[1], w2 = sw[2];
    const float* xb = x + (size_t)b * kCin * kL;

    floatx4 accY[4][4], accR[4][4];
    #pragma unroll
    for (int mi = 0; mi < 4; ++mi)
        #pragma unroll
        for (int ni = 0; ni < 4; ++ni) {
            accY[mi][ni] = (floatx4){0.f, 0.f, 0.f, 0.f};
            accR[mi][ni] = (floatx4){0.f, 0.f, 0.f, 0.f};
        }

    const int gsw = (((lane & 3) ^ ((lane >> 3) & 3)) * 8);
    const unsigned short* wsrc[4];
    unsigned short* wdst[4];
    #pragma unroll
    for (int j = 0; j < 4; ++j) {
        const int m = j >> 1;
        const int r = (j & 1) * 64 + wave * 16 + (lane >> 2);
        wsrc[j] = Wbf + (size_t)m * 131072 + (size_t)(o0 + r) * kCin + gsw;
        wdst[j] = As + j * 2048 + wave * 512;
    }

    const int rsw = (fr >> 1) & 3;
    int aOffP[4], bOff[4];
    #pragma unroll
    for (int mi = 0; mi < 4; ++mi)
        aOffP[mi] = (wo + mi * 16 + fr) * 32 + ((fq ^ rsw) * 8);
    #pragma unroll
    for (int ni = 0; ni < 4; ++ni) bOff[ni] = (wl + ni * 16 + fr) * ST + fq * 8;

    const int c2 = (tid & 15) * 2;
    const int ll = (tid >> 4) * 8;
    const bool hasprv = (l0 + ll) >= 4;
    float4 xpa, xa0, xa1, xpb, xb0, xb1;
    auto LOAD = [&](int ks) {
        const int k0 = ks * BK;
        const float* base0 = xb + (size_t)(k0 + c2) * kL + l0 + ll;
        const float* base1 = base0 + kL;
        xpa = hasprv ? *(const float4*)(base0 - 4) : make_float4(0.f,0.f,0.f,0.f);
        xa0 = *(const float4*)(base0);
        xa1 = *(const float4*)(base0 + 4);
        xpb = hasprv ? *(const float4*)(base1 - 4) : make_float4(0.f,0.f,0.f,0.f);
        xb0 = *(const float4*)(base1);
        xb1 = *(const float4*)(base1 + 4);
    };
    auto PACKB = [&]() {
        float A[12]  = {xpa.x,xpa.y,xpa.z,xpa.w, xa0.x,xa0.y,xa0.z,xa0.w, xa1.x,xa1.y,xa1.z,xa1.w};
        float Bv[12] = {xpb.x,xpb.y,xpb.z,xpb.w, xb0.x,xb0.y,xb0.z,xb0.w, xb1.x,xb1.y,xb1.z,xb1.w};
        #pragma unroll
        for (int j = 0; j < 8; ++j) {
            float zA = fmaf(w0, A[j],  fmaf(w1, A[j + 2],  w2 * A[j + 4]));
            float zB = fmaf(w0, Bv[j], fmaf(w1, Bv[j + 2], w2 * Bv[j + 4]));
            *(unsigned*)&Bz[(ll + j) * ST + c2] = cvtpk(zA, zB);
            *(unsigned*)&Bx[(ll + j) * ST + c2] = cvtpk(A[j + 4], Bv[j + 4]);
        }
    };

    LOAD(0);
    for (int ks = 0; ks < KSTEPS; ++ks) {
        #pragma unroll
        for (int j = 0; j < 4; ++j) { cp16(wsrc[j], wdst[j]); wsrc[j] += BK; }
        PACKB();
        __syncthreads();
        if (ks < KSTEPS - 1) LOAD(ks + 1);
        short8 vz[4], vx[4];
        #pragma unroll
        for (int ni = 0; ni < 4; ++ni) {
            vz[ni] = *(const short8*)&Bz[bOff[ni]];
            vx[ni] = *(const short8*)&Bx[bOff[ni]];
        }
        #pragma unroll
        for (int mi = 0; mi < 4; ++mi) {
            short8 ap = *(const short8*)&As[aOffP[mi]];
            short8 ar = *(const short8*)&As[4096 + aOffP[mi]];
            #pragma unroll
            for (int ni = 0; ni < 4; ++ni) {
                accY[mi][ni] = __builtin_amdgcn_mfma_f32_16x16x32_bf16(ap, vz[ni], accY[mi][ni], 0, 0, 0);
                accR[mi][ni] = __builtin_amdgcn_mfma_f32_16x16x32_bf16(ar, vx[ni], accR[mi][ni], 0, 0, 0);
            }
        }
        __syncthreads();
    }

    #pragma unroll
    for (int mi = 0; mi < 4; ++mi)
        #pragma unroll
        for (int r = 0; r < 4; ++r) {
            const int o = o0 + wo + mi * 16 + fq * 4 + r;
            const float sc = sc_arr[o], sh = sh_arr[o], rb = res_b[o];
            const size_t orow = ((size_t)b * kCout + o) * kL + l0 + wl + fr;
            #pragma unroll
            for (int ni = 0; ni < 4; ++ni) {
                float yn = fmaxf(fmaf(accY[mi][ni][r], sc, sh), 0.f);
                float rr = accR[mi][ni][r] + rb;
                out[orow + ni * 16] = fmaxf(yn + rr, 0.f);
            }
        }
}

extern "C" void kernel_launch(void* const* d_in, const int* in_sizes, int n_in,
                              void* d_out, int out_size, void* d_ws, size_t ws_size,
                              hipStream_t stream)
{
    (void)in_sizes; (void)n_in; (void)out_size;
    const float* x     = (const float*)d_in[0];
    const float* sw    = (const float*)d_in[1];
    const float* pw_w  = (const float*)d_in[2];
    const float* gamma = (const float*)d_in[4];
    const float* beta  = (const float*)d_in[5];
    const float* res_w = (const float*)d_in[6];
    const float* res_b = (const float*)d_in[7];
    float* out = (float*)d_out;
    float* wsf = (float*)d_ws;

    if (ws_size >= W_BYTES) {
        unsigned short* Wbf = (unsigned short*)(wsf + W_WBF);
        unsigned short* Zc  = (unsigned short*)(wsf + W_ZC);
        k_prep<<<8352, 256, 0, stream>>>(x, sw, pw_w, res_w, Zc, wsf + W_SZP, Wbf, wsf + W_G);
        k_gramA<<<256, 256, 0, stream>>>(Zc, wsf + W_G);
        k_bnp2<<<kCout, 256, 0, stream>>>(wsf + W_G, wsf + W_SZP, Wbf, gamma, beta,
                                          wsf + W_SC, wsf + W_SH);
        k_out2<<<GRID_OUT, 256, 0, stream>>>(x, sw, Wbf, res_b,
                                             wsf + W_SC, wsf + W_SH, out);
    } else {
        unsigned short* Wbf = (unsigned short*)(wsf + F_WBF);
        k_init<<<161, 256, 0, stream>>>(pw_w, res_w, Wbf, wsf + F_SZ, wsf + F_G);
        k_gram_fb<<<512, 256, 0, stream>>>(x, sw, wsf + F_G, wsf + F_SZ);
        k_bnp<<<kCout, 256, 0, stream>>>(wsf + F_G, wsf + F_SZ, Wbf, gamma, beta,
                                         wsf + F_SC, wsf + F_SH);
        k_out2<<<GRID_OUT, 256, 0, stream>>>(x, sw, Wbf, res_b,
                                             wsf + F_SC, wsf + F_SH, out);
    }
}